// Round 12
// baseline (143.451 us; speedup 1.0000x reference)
//
#include <hip/hip_runtime.h>
#include <stdint.h>

#define NA   16000
#define KNN  10
#define NRES 400
#define APR  40
#define NCAT 12
#define BERT 1024
#define FF   128
#define DF1  256
#define DF2  64

using short8   = __attribute__((ext_vector_type(8))) short;
using floatx4  = __attribute__((ext_vector_type(4))) float;
using ushort4v = __attribute__((ext_vector_type(4))) unsigned short;
using ushort8v = __attribute__((ext_vector_type(8))) unsigned short;

__device__ __forceinline__ unsigned short bfc(float v) {
    return __builtin_bit_cast(unsigned short, (__bf16)v);
}
__device__ __forceinline__ float bflo(uint32_t u){ return __uint_as_float(u << 16); }
__device__ __forceinline__ float bfhi(uint32_t u){ return __uint_as_float(u & 0xffff0000u); }

// async global->LDS, 16B per lane
__device__ __forceinline__ void gload16(void* lds, const void* g) {
    __builtin_amdgcn_global_load_lds(
        (const __attribute__((address_space(1))) uint32_t*)g,
        (__attribute__((address_space(3))) uint32_t*)lds, 16, 0, 0);
}

// ---------------------------------------------------------------------------
// Weight prep.
// WrT: 4 k-chunks x swizzled [128 n][256 k] bf16 image (64 KB each); a LINEAR
//      copy into LDS reproduces byte (n*512 + k*2)^((n&7)<<4).
// Bt3: 3 mats x 2 pre-swizzled 128x64 tiles (k_gemm_l2 gload staging).
// W2T: [64][256] linear bf16.
// ---------------------------------------------------------------------------
__global__ void k_prep(const float* __restrict__ Wr,
                       const float* __restrict__ Wsv, const float* __restrict__ Wsr2,
                       const float* __restrict__ Wdr2, const float* __restrict__ Wf2,
                       unsigned short* __restrict__ WrT, unsigned short* __restrict__ Bt3,
                       unsigned short* __restrict__ W2T)
{
    int idx = blockIdx.x * 256 + threadIdx.x;
    if (idx < 16384) {                       // WrT: 4 chunks x 128 n x 32 kq
        int c = idx >> 12, rem = idx & 4095, n = rem >> 5, kq = rem & 31;
        ushort8v v;
#pragma unroll
        for (int e = 0; e < 8; ++e)
            v[e] = bfc(Wr[(size_t)(c * 256 + kq * 8 + e) * FF + n]);
        int ba = c * 65536 + ((n * 512 + kq * 16) ^ ((n & 7) << 4));
        *(ushort8v*)((char*)WrT + ba) = v;
    } else if (idx < 16384 + 6144) {         // Bt3: 3 mats x 2 tiles x 128 x 8
        int i2 = idx - 16384;
        int m = i2 >> 11, r2 = i2 & 2047;
        int t = r2 >> 10, r3 = r2 & 1023, n = r3 >> 3, kq = r3 & 7;
        const float* W = (m == 0) ? Wsv : ((m == 1) ? Wsr2 : Wdr2);
        ushort8v v;
#pragma unroll
        for (int e = 0; e < 8; ++e)
            v[e] = bfc(W[(size_t)(t * 64 + kq * 8 + e) * FF + n]);
        int ba = (m * 2 + t) * 16384 + ((n * 128 + kq * 16) ^ ((n & 7) << 4));
        *(ushort8v*)((char*)Bt3 + ba) = v;
    } else {                                 // W2T
        int i3 = idx - 16384 - 6144;
        int n = i3 >> 8, k = i3 & 255;
        W2T[i3] = bfc(Wf2[(size_t)k * DF2 + n]);
    }
}

// ---------------------------------------------------------------------------
// SD[a][0:128]=bf16(atoms@Wsr1), [128:256]=bf16(atoms@Wdr1).
// ---------------------------------------------------------------------------
__global__ void __launch_bounds__(256)
k_atomsSD(const float* __restrict__ atoms0, const float* __restrict__ atoms1,
          const float* __restrict__ Wsr1, const float* __restrict__ Wdr1,
          unsigned short* __restrict__ SD)
{
    __shared__ float sAt[64 * NCAT];   // 3 KB
    const int p = blockIdx.y;
    const float* atoms = p ? atoms1 : atoms0;
    unsigned short* SDp = SD + (size_t)p * 4096000;
    const int a0 = blockIdx.x * 64;
    const int tid = threadIdx.x;
    const int f = tid & 127, half = tid >> 7;

    if (tid < 192)
        ((float4*)sAt)[tid] = *(const float4*)&atoms[(size_t)a0 * NCAT + tid * 4];

    float wsr[NCAT], wdr[NCAT];
#pragma unroll
    for (int c = 0; c < NCAT; ++c) {
        wsr[c] = Wsr1[c * FF + f];
        wdr[c] = Wdr1[c * FF + f];
    }
    __syncthreads();

#pragma unroll 4
    for (int pass = 0; pass < 32; ++pass) {
        int ai = pass * 2 + half;
        int a = a0 + ai;
        float ss = 0.f, sd = 0.f;
#pragma unroll
        for (int c = 0; c < NCAT; ++c) {
            float ac = sAt[ai * NCAT + c];
            ss = fmaf(ac, wsr[c], ss);
            sd = fmaf(ac, wdr[c], sd);
        }
        SDp[(size_t)a * 256 + f]       = bfc(ss);
        SDp[(size_t)a * 256 + 128 + f] = bfc(sd);
    }
}

// ---------------------------------------------------------------------------
// Big GEMM: residues[16000,1024] @ Wr, split-K x4, 64 KB B-chunk LDS-resident.
// 512 threads (8 waves); stage once, ONE barrier, then barrier-free: each
// wave owns a 32-row m-unit with a manual 4-deep A-prefetch register ring
// (statically unrolled).  blockIdx: x m-range, y = k-chunk (K=256), z = prot.
// Partial kc -> P[kc] (summed in k_gather1).
// ---------------------------------------------------------------------------
__global__ void __launch_bounds__(512, 3)
k_gemm_big(const float* __restrict__ R0, const float* __restrict__ R1,
           const unsigned short* __restrict__ WrT, float* __restrict__ P)
{
    __shared__ __align__(16) unsigned short sB[32768];   // 64 KB
    const int tid = threadIdx.x, l = tid & 63, w = tid >> 6;
    const int kc = blockIdx.y;
    const float* A = blockIdx.z ? R1 : R0;
    float* C = P + ((size_t)kc * 2 + blockIdx.z) * 2048000;
    const int lr = l & 15, lq = l >> 4;

    // ---- stage B chunk once (linear copy of pre-swizzled 64 KB image) ----
    {
        const char* bs = (const char*)WrT + (size_t)kc * 65536 + tid * 16;
        char* bd = (char*)sB + tid * 16;
#pragma unroll
        for (int q = 0; q < 8; ++q) gload16(bd + q * 8192, bs + q * 8192);
    }
    __syncthreads();   // only barrier in the kernel

    const int g = blockIdx.x * 8 + w;       // m-unit id
    if (g >= 500) return;
    const int m0 = g * 32;

    const float* ap0 = A + (size_t)(m0 + lr) * BERT + kc * 256 + lq * 8;
    const float* ap1 = ap0 + (size_t)16 * BERT;

    floatx4 acc[2][8];
#pragma unroll
    for (int s = 0; s < 2; ++s)
#pragma unroll
        for (int nt = 0; nt < 8; ++nt) acc[s][nt] = (floatx4){0.f, 0.f, 0.f, 0.f};

    // 4-deep prefetch ring (all indices static after unroll)
    float4 ar0[4][2], ar1[4][2];
#pragma unroll
    for (int j = 0; j < 4; ++j) {
        ar0[j][0] = *(const float4*)(ap0 + j * 32);
        ar0[j][1] = *(const float4*)(ap0 + j * 32 + 4);
        ar1[j][0] = *(const float4*)(ap1 + j * 32);
        ar1[j][1] = *(const float4*)(ap1 + j * 32 + 4);
    }

#pragma unroll
    for (int kt = 0; kt < 8; ++kt) {
        const int sl = kt & 3;
        short8 af0, af1;
        {
            float4 x0 = ar0[sl][0], x1 = ar0[sl][1];
            float4 y0 = ar1[sl][0], y1 = ar1[sl][1];
            af0[0] = (short)bfc(x0.x); af0[1] = (short)bfc(x0.y);
            af0[2] = (short)bfc(x0.z); af0[3] = (short)bfc(x0.w);
            af0[4] = (short)bfc(x1.x); af0[5] = (short)bfc(x1.y);
            af0[6] = (short)bfc(x1.z); af0[7] = (short)bfc(x1.w);
            af1[0] = (short)bfc(y0.x); af1[1] = (short)bfc(y0.y);
            af1[2] = (short)bfc(y0.z); af1[3] = (short)bfc(y0.w);
            af1[4] = (short)bfc(y1.x); af1[5] = (short)bfc(y1.y);
            af1[6] = (short)bfc(y1.z); af1[7] = (short)bfc(y1.w);
        }
        if (kt < 4) {   // refill slot with kt+4
            ar0[sl][0] = *(const float4*)(ap0 + (kt + 4) * 32);
            ar0[sl][1] = *(const float4*)(ap0 + (kt + 4) * 32 + 4);
            ar1[sl][0] = *(const float4*)(ap1 + (kt + 4) * 32);
            ar1[sl][1] = *(const float4*)(ap1 + (kt + 4) * 32 + 4);
        }
#pragma unroll
        for (int nt = 0; nt < 8; ++nt) {
            int n = nt * 16 + lr;
            short8 bf = *(const short8*)((char*)sB +
                        ((n * 512 + kt * 64 + lq * 16) ^ ((n & 7) << 4)));
            acc[0][nt] = __builtin_amdgcn_mfma_f32_16x16x32_bf16(af0, bf, acc[0][nt], 0, 0, 0);
            acc[1][nt] = __builtin_amdgcn_mfma_f32_16x16x32_bf16(af1, bf, acc[1][nt], 0, 0, 0);
        }
    }

#pragma unroll
    for (int s = 0; s < 2; ++s)
#pragma unroll
        for (int nt = 0; nt < 8; ++nt)
#pragma unroll
            for (int r = 0; r < 4; ++r)
                C[(size_t)(m0 + s * 16 + lq * 4 + r) * FF + nt * 16 + lr] = acc[s][nt][r];
}

// ---------------------------------------------------------------------------
// Layer-2 GEMM (unchanged): Z(pre-swizzled bf16 tiles) @ {Wsv,Wsr2,Wdr2}.
// ---------------------------------------------------------------------------
__global__ void __launch_bounds__(256)
k_gemm_l2(const unsigned short* __restrict__ Zsw, const unsigned short* __restrict__ Bt3,
          float* __restrict__ ACC, unsigned short* __restrict__ SD)
{
    __shared__ __align__(16) unsigned short sA[2][32 * 64];   // 2 x 4 KB
    __shared__ __align__(16) unsigned short sB[2][128 * 64];  // 2 x 16 KB
    const int tid = threadIdx.x, l = tid & 63, w = tid >> 6;
    const int m0 = blockIdx.x * 32;
    const int mat = blockIdx.y, p = blockIdx.z;
    const unsigned short* Zp = Zsw + (size_t)p * 2048000;

    floatx4 acc[2][2];
#pragma unroll
    for (int mt = 0; mt < 2; ++mt)
#pragma unroll
        for (int nt = 0; nt < 2; ++nt) acc[mt][nt] = (floatx4){0.f, 0.f, 0.f, 0.f};

#pragma unroll
    for (int t = 0; t < 2; ++t) {
        const char* bs = (const char*)Bt3 + (size_t)(mat * 2 + t) * 16384 + tid * 16;
#pragma unroll
        for (int q = 0; q < 4; ++q) gload16((char*)sB[t] + tid * 16 + q * 4096, bs + q * 4096);
        gload16((char*)sA[t] + tid * 16,
                (const char*)Zp + (size_t)((m0 >> 5) * 2 + t) * 4096 + tid * 16);
    }
    __syncthreads();

#pragma unroll
    for (int t = 0; t < 2; ++t)
#pragma unroll
        for (int ks = 0; ks < 2; ++ks) {
            short8 ah[2], bh[2];
            const int kb = ks * 64 + (l >> 4) * 16;
#pragma unroll
            for (int mt = 0; mt < 2; ++mt) {
                int row = mt * 16 + (l & 15);
                ah[mt] = *(const short8*)((char*)sA[t] + ((row * 128 + kb) ^ ((row & 7) << 4)));
            }
#pragma unroll
            for (int nt = 0; nt < 2; ++nt) {
                int row = w * 32 + nt * 16 + (l & 15);
                bh[nt] = *(const short8*)((char*)sB[t] + ((row * 128 + kb) ^ ((row & 7) << 4)));
            }
#pragma unroll
            for (int mt = 0; mt < 2; ++mt)
#pragma unroll
                for (int nt = 0; nt < 2; ++nt)
                    acc[mt][nt] = __builtin_amdgcn_mfma_f32_16x16x32_bf16(ah[mt], bh[nt], acc[mt][nt], 0, 0, 0);
        }

    float* ACCp = ACC + (size_t)p * 2048000;
    unsigned short* SDp = (unsigned short*)SD + (size_t)p * 4096000;
#pragma unroll
    for (int mt = 0; mt < 2; ++mt)
#pragma unroll
        for (int nt = 0; nt < 2; ++nt)
#pragma unroll
            for (int r = 0; r < 4; ++r) {
                int row = m0 + mt * 16 + (l >> 4) * 4 + r;
                int col = w * 32 + nt * 16 + (l & 15);
                float v = acc[mt][nt][r];
                if (mat == 0) ACCp[(size_t)row * FF + col] = v;
                else          SDp [(size_t)row * 256 + (mat - 1) * FF + col] = bfc(v);
            }
}

// ---------------------------------------------------------------------------
// Gather 1: Z = relu(P0+P1+P2+P3 + atoms@Wv + mean(S,sn) + mean(D,dn)) -> Zsw
// ---------------------------------------------------------------------------
__global__ void __launch_bounds__(256)
k_gather1(const float* __restrict__ P0, const float* __restrict__ P1,
          const float* __restrict__ P2, const float* __restrict__ P3,
          const unsigned short* __restrict__ SD,
          const int* __restrict__ sn0, const int* __restrict__ dn0,
          const int* __restrict__ sn1, const int* __restrict__ dn1,
          const float* __restrict__ atoms0, const float* __restrict__ atoms1,
          const float* __restrict__ Wv, unsigned short* __restrict__ Zout)
{
    __shared__ int sIdx[16][20];
    __shared__ float sWv[NCAT * FF];   // 6 KB
    __shared__ float sAt[16 * NCAT];   // 768 B
    const int tid = threadIdx.x;
    const int p = blockIdx.y;
    const int a0 = blockIdx.x * 16;
    const int* sn = p ? sn1 : sn0;
    const int* dn = p ? dn1 : dn0;
    const size_t po = (size_t)p * 2048000;
    const unsigned short* SDp = SD + (size_t)p * 4096000;
    unsigned short* Zp = Zout + po;

    for (int t = tid; t < 320; t += 256) {
        int at = t / 20, q = t - at * 20;
        sIdx[at][q] = (q < 10) ? sn[(a0 + at) * KNN + q] : dn[(a0 + at) * KNN + q - 10];
    }
    {
        const float* atoms = p ? atoms1 : atoms0;
        for (int i = tid; i < 384; i += 256)
            ((float4*)sWv)[i] = ((const float4*)Wv)[i];
        if (tid < 48) {
            int at = tid / 3, q = tid - at * 3;
            *(float4*)&sAt[at * NCAT + q * 4] =
                *(const float4*)&atoms[(size_t)(a0 + at) * NCAT + q * 4];
        }
    }
    __syncthreads();
    const int at = tid >> 4, c8 = tid & 15;
    const int a = a0 + at;
    float ss[8] = {0,0,0,0,0,0,0,0}, dd[8] = {0,0,0,0,0,0,0,0};
    int sc = 0, dc = 0;
#pragma unroll
    for (int n = 0; n < KNN; ++n) {
        int is = sIdx[at][n];
        if (is > -1) {
            sc++;
            uint4 v = *(const uint4*)&SDp[(size_t)is * 256 + c8 * 8];
            uint32_t vv[4] = {v.x, v.y, v.z, v.w};
#pragma unroll
            for (int q = 0; q < 4; ++q) { ss[2*q] += bflo(vv[q]); ss[2*q+1] += bfhi(vv[q]); }
        }
    }
#pragma unroll
    for (int n = 0; n < KNN; ++n) {
        int id = sIdx[at][10 + n];
        if (id > -1) {
            dc++;
            uint4 v = *(const uint4*)&SDp[(size_t)id * 256 + 128 + c8 * 8];
            uint32_t vv[4] = {v.x, v.y, v.z, v.w};
#pragma unroll
            for (int q = 0; q < 4; ++q) { dd[2*q] += bflo(vv[q]); dd[2*q+1] += bfhi(vv[q]); }
        }
    }
    const float rs = 1.f / (sc > 0 ? (float)sc : 1.f);
    const float rd = 1.f / (dc > 0 ? (float)dc : 1.f);
    float ov[8];
    {
        const size_t base = po + (size_t)a * FF + c8 * 8;
        float4 q00 = *(const float4*)&P0[base],     q01 = *(const float4*)&P0[base + 4];
        float4 q10 = *(const float4*)&P1[base],     q11 = *(const float4*)&P1[base + 4];
        float4 q20 = *(const float4*)&P2[base],     q21 = *(const float4*)&P2[base + 4];
        float4 q30 = *(const float4*)&P3[base],     q31 = *(const float4*)&P3[base + 4];
        ov[0] = (q00.x + q10.x) + (q20.x + q30.x);
        ov[1] = (q00.y + q10.y) + (q20.y + q30.y);
        ov[2] = (q00.z + q10.z) + (q20.z + q30.z);
        ov[3] = (q00.w + q10.w) + (q20.w + q30.w);
        ov[4] = (q01.x + q11.x) + (q21.x + q31.x);
        ov[5] = (q01.y + q11.y) + (q21.y + q31.y);
        ov[6] = (q01.z + q11.z) + (q21.z + q31.z);
        ov[7] = (q01.w + q11.w) + (q21.w + q31.w);
    }
#pragma unroll
    for (int c = 0; c < NCAT; ++c) {
        float ac = sAt[at * NCAT + c];
        float4 w0 = *(const float4*)&sWv[c * FF + c8 * 8];
        float4 w1 = *(const float4*)&sWv[c * FF + c8 * 8 + 4];
        ov[0] = fmaf(ac, w0.x, ov[0]); ov[1] = fmaf(ac, w0.y, ov[1]);
        ov[2] = fmaf(ac, w0.z, ov[2]); ov[3] = fmaf(ac, w0.w, ov[3]);
        ov[4] = fmaf(ac, w1.x, ov[4]); ov[5] = fmaf(ac, w1.y, ov[5]);
        ov[6] = fmaf(ac, w1.z, ov[6]); ov[7] = fmaf(ac, w1.w, ov[7]);
    }
    ushort8v zv;
#pragma unroll
    for (int e = 0; e < 8; ++e)
        zv[e] = bfc(fmaxf(fmaf(ss[e], rs, fmaf(dd[e], rd, ov[e])), 0.f));
    int ba = ((a >> 5) * 2 + (c8 >> 3)) * 4096
           + (((a & 31) * 128 + (c8 & 7) * 16) ^ ((a & 7) << 4));
    *(ushort8v*)((char*)Zp + ba) = zv;
}

// ---------------------------------------------------------------------------
// Gather 2 fused with residue mean: one block per residue (40 atoms).
// ---------------------------------------------------------------------------
__global__ void __launch_bounds__(256)
k_gather_res(const float* __restrict__ ACC, const unsigned short* __restrict__ SD,
             const int* __restrict__ sn0, const int* __restrict__ dn0,
             const int* __restrict__ sn1, const int* __restrict__ dn1,
             float* __restrict__ R12)
{
    __shared__ int sIdx[APR][20];      // 3.2 KB
    __shared__ float zpart[16][128];   // 8 KB
    const int tid = threadIdx.x;
    const int p = blockIdx.y, r = blockIdx.x;
    const int* sn = p ? sn1 : sn0;
    const int* dn = p ? dn1 : dn0;
    const float* ACCp = ACC + (size_t)p * 2048000;
    const unsigned short* SDp = SD + (size_t)p * 4096000;
    const int aBase = r * APR;

    for (int t = tid; t < APR * 20; t += 256) {
        int at = t / 20, q = t - at * 20;
        sIdx[at][q] = (q < 10) ? sn[(aBase + at) * KNN + q] : dn[(aBase + at) * KNN + q - 10];
    }
    __syncthreads();

    const int at = tid >> 4, c8 = tid & 15;
    float zs[8] = {0,0,0,0,0,0,0,0};
#pragma unroll
    for (int rep = 0; rep < 3; ++rep) {
        int ai = at + rep * 16;
        if (ai < APR) {
            int a = aBase + ai;
            float ss[8] = {0,0,0,0,0,0,0,0}, dd[8] = {0,0,0,0,0,0,0,0};
            int sc = 0, dc = 0;
#pragma unroll
            for (int n = 0; n < KNN; ++n) {
                int is = sIdx[ai][n];
                if (is > -1) {
                    sc++;
                    uint4 v = *(const uint4*)&SDp[(size_t)is * 256 + c8 * 8];
                    uint32_t vv[4] = {v.x, v.y, v.z, v.w};
#pragma unroll
                    for (int q = 0; q < 4; ++q) { ss[2*q] += bflo(vv[q]); ss[2*q+1] += bfhi(vv[q]); }
                }
            }
#pragma unroll
            for (int n = 0; n < KNN; ++n) {
                int id = sIdx[ai][10 + n];
                if (id > -1) {
                    dc++;
                    uint4 v = *(const uint4*)&SDp[(size_t)id * 256 + 128 + c8 * 8];
                    uint32_t vv[4] = {v.x, v.y, v.z, v.w};
#pragma unroll
                    for (int q = 0; q < 4; ++q) { dd[2*q] += bflo(vv[q]); dd[2*q+1] += bfhi(vv[q]); }
                }
            }
            const float rs = 1.f / (sc > 0 ? (float)sc : 1.f);
            const float rd = 1.f / (dc > 0 ? (float)dc : 1.f);
            float4 a0v = *(const float4*)&ACCp[(size_t)a * FF + c8 * 8];
            float4 a1v = *(const float4*)&ACCp[(size_t)a * FF + c8 * 8 + 4];
            float ov[8] = {a0v.x, a0v.y, a0v.z, a0v.w, a1v.x, a1v.y, a1v.z, a1v.w};
#pragma unroll
            for (int e = 0; e < 8; ++e)
                zs[e] += fmaxf(fmaf(ss[e], rs, fmaf(dd[e], rd, ov[e])), 0.f);
        }
    }
    *(float4*)&zpart[at][c8 * 8]     = (float4){zs[0], zs[1], zs[2], zs[3]};
    *(float4*)&zpart[at][c8 * 8 + 4] = (float4){zs[4], zs[5], zs[6], zs[7]};
    __syncthreads();
#pragma unroll
    for (int s = 8; s > 0; s >>= 1) {
        if (at < s) {
            float4 x0 = *(const float4*)&zpart[at + s][c8 * 8];
            float4 x1 = *(const float4*)&zpart[at + s][c8 * 8 + 4];
            float4 y0 = *(const float4*)&zpart[at][c8 * 8];
            float4 y1 = *(const float4*)&zpart[at][c8 * 8 + 4];
            y0.x += x0.x; y0.y += x0.y; y0.z += x0.z; y0.w += x0.w;
            y1.x += x1.x; y1.y += x1.y; y1.z += x1.z; y1.w += x1.w;
            *(float4*)&zpart[at][c8 * 8]     = y0;
            *(float4*)&zpart[at][c8 * 8 + 4] = y1;
        }
        __syncthreads();
    }
    if (at == 0) {
        float* R = R12 + (size_t)p * 51200 + (size_t)r * FF;
        const float inv = 1.0f / APR;
#pragma unroll
        for (int e = 0; e < 8; ++e) R[c8 * 8 + e] = zpart[0][c8 * 8 + e] * inv;
    }
}

// ---------------------------------------------------------------------------
// A1[i] = r1[i] @ Wf1[:128,:] + bf1 ;  B1[j] = r2[j] @ Wf1[128:,:]
// ---------------------------------------------------------------------------
__global__ void k_pairprep(const float* __restrict__ R1, const float* __restrict__ R2,
                           const float* __restrict__ Wf1, const float* __restrict__ bf1,
                           float* __restrict__ A1, float* __restrict__ B1)
{
    __shared__ float r1s[FF], r2s[FF];
    int i = blockIdx.x, o = threadIdx.x;   // 256 threads
    if (o < FF) r1s[o] = R1[i * FF + o];
    else        r2s[o - FF] = R2[i * FF + (o - FF)];
    __syncthreads();
    float sa = bf1[o], sb = 0.f;
#pragma unroll 8
    for (int k = 0; k < FF; ++k) {
        sa = fmaf(r1s[k], Wf1[(size_t)k * DF1 + o], sa);
        sb = fmaf(r2s[k], Wf1[(size_t)(FF + k) * DF1 + o], sb);
    }
    A1[(size_t)i * DF1 + o] = sa;
    B1[(size_t)i * DF1 + o] = sb;
}

// ---------------------------------------------------------------------------
// Pair MLP via MFMA, register-built H.
// ---------------------------------------------------------------------------
__global__ void __launch_bounds__(256)
k_pairs_mfma(const float* __restrict__ A1, const float* __restrict__ B1,
             const unsigned short* __restrict__ W2T,
             const float* __restrict__ bf2, const float* __restrict__ Wf3,
             const float* __restrict__ bf3, float* __restrict__ out)
{
    __shared__ __align__(16) float sA1[16 * 256];            // 16 KB linear
    __shared__ __align__(16) float sB1[16 * 256];            // 16 KB, XOR (row&7)<<5
    __shared__ __align__(16) unsigned short sW[64 * 256];    // 32 KB, XOR (n&7)<<4
    const int tid = threadIdx.x, l = tid & 63, w = tid >> 6;
    const int i0 = blockIdx.x * 16, j0 = blockIdx.y * 16;

    for (int idx = tid; idx < 64 * 32; idx += 256) {
        int row = idx >> 5, c = idx & 31;
        int ba = (row * 512 + c * 16) ^ ((row & 7) << 4);
        *(uint4*)((char*)sW + ba) = *(const uint4*)(W2T + row * 256 + c * 8);
    }
    {
        int row = tid >> 4;
#pragma unroll
        for (int pass = 0; pass < 4; ++pass) {
            int coff = pass * 64 + (tid & 15) * 4;
            *(float4*)((char*)sA1 + row * 1024 + coff * 4) =
                *(const float4*)&A1[(size_t)(i0 + row) * DF1 + coff];
            int bb = (row * 1024 + coff * 4) ^ ((row & 7) << 5);
            *(float4*)((char*)sB1 + bb) =
                *(const float4*)&B1[(size_t)(j0 + row) * DF1 + coff];
        }
    }
    __syncthreads();

    floatx4 acc[4][4];
#pragma unroll
    for (int mt = 0; mt < 4; ++mt)
#pragma unroll
        for (int nt = 0; nt < 4; ++nt) acc[mt][nt] = (floatx4){0.f, 0.f, 0.f, 0.f};

    float b2r[4], w3r[4];
#pragma unroll
    for (int nt = 0; nt < 4; ++nt) {
        b2r[nt] = bf2[nt * 16 + (l & 15)];
        w3r[nt] = Wf3[nt * 16 + (l & 15)];
    }

    const int rB = l & 15, kq = l >> 4;
#pragma unroll
    for (int kc = 0; kc < 4; ++kc)
#pragma unroll
        for (int ks = 0; ks < 2; ++ks) {
            const int kfb = (kc * 64 + ks * 32 + kq * 8) * 4;
            float4 b1a = *(const float4*)((char*)sB1 + ((rB * 1024 + kfb)      ^ ((rB & 7) << 5)));
            float4 b1b = *(const float4*)((char*)sB1 + ((rB * 1024 + kfb + 16) ^ ((rB & 7) << 5)));
            short8 afr[4];
#pragma unroll
            for (int mt = 0; mt < 4; ++mt) {
                int rA = w * 4 + mt;
                float4 a1a = *(const float4*)((char*)sA1 + rA * 1024 + kfb);
                float4 a1b = *(const float4*)((char*)sA1 + rA * 1024 + kfb + 16);
                short8 hv;
                hv[0] = (short)bfc(fmaxf(a1a.x + b1a.x, 0.f));
                hv[1] = (short)bfc(fmaxf(a1a.y + b1a.y, 0.f));
                hv[2] = (short)bfc(fmaxf(a1a.z + b1a.z, 0.f));
                hv[3] = (short)bfc(fmaxf(a1a.w + b1a.w, 0.f));
                hv[4] = (short)bfc(fmaxf(a1b.x + b1b.x, 0.f));
                hv[5] = (short)bfc(fmaxf(a1b.y + b1b.y, 0.f));
                hv[6] = (short)bfc(fmaxf(a1b.z + b1b.z, 0.f));
                hv[7] = (short)bfc(fmaxf(a1b.w + b1b.w, 0.f));
                afr[mt] = hv;
            }
            const int kwb = kc * 128 + ks * 64 + kq * 16;
            short8 bfr[4];
#pragma unroll
            for (int nt = 0; nt < 4; ++nt) {
                int n = nt * 16 + (l & 15);
                bfr[nt] = *(const short8*)((char*)sW + ((n * 512 + kwb) ^ ((n & 7) << 4)));
            }
#pragma unroll
            for (int mt = 0; mt < 4; ++mt)
#pragma unroll
                for (int nt = 0; nt < 4; ++nt)
                    acc[mt][nt] = __builtin_amdgcn_mfma_f32_16x16x32_bf16(afr[mt], bfr[nt], acc[mt][nt], 0, 0, 0);
        }

    const float b3 = bf3[0];
#pragma unroll
    for (int mt = 0; mt < 4; ++mt)
#pragma unroll
        for (int r = 0; r < 4; ++r) {
            float s = 0.f;
#pragma unroll
            for (int nt = 0; nt < 4; ++nt)
                s += fmaxf(acc[mt][nt][r] + b2r[nt], 0.f) * w3r[nt];
            s += __shfl_xor(s, 1); s += __shfl_xor(s, 2);
            s += __shfl_xor(s, 4); s += __shfl_xor(s, 8);
            if ((l & 15) == 0) {
                int p = w * 64 + mt * 16 + (l >> 4) * 4 + r;
                out[(size_t)(i0 + (p >> 4)) * NRES + j0 + (p & 15)] = s + b3;
            }
        }
}

// ---------------------------------------------------------------------------
extern "C" void kernel_launch(void* const* d_in, const int* in_sizes, int n_in,
                              void* d_out, int out_size, void* d_ws, size_t ws_size,
                              hipStream_t stream)
{
    const float* atoms0    = (const float*)d_in[0];
    const float* residues0 = (const float*)d_in[1];
    const int*   same0     = (const int*)d_in[2];
    const int*   diff0     = (const int*)d_in[3];
    const float* atoms1    = (const float*)d_in[5];
    const float* residues1 = (const float*)d_in[6];
    const int*   same1     = (const int*)d_in[7];
    const int*   diff1     = (const int*)d_in[8];
    const float* Wv   = (const float*)d_in[10];
    const float* Wr   = (const float*)d_in[11];
    const float* Wsr1 = (const float*)d_in[12];
    const float* Wdr1 = (const float*)d_in[13];
    const float* Wsv  = (const float*)d_in[14];
    const float* Wsr2 = (const float*)d_in[15];
    const float* Wdr2 = (const float*)d_in[16];
    const float* Wf1  = (const float*)d_in[17];
    const float* bf1  = (const float*)d_in[18];
    const float* Wf2  = (const float*)d_in[19];
    const float* bf2  = (const float*)d_in[20];
    const float* Wf3  = (const float*)d_in[21];
    const float* bf3  = (const float*)d_in[22];

    float* ws  = (float*)d_ws;
    float* P0 = ws;                  // = ACC, 2 x 2,048,000 f
    float* P1 = ws + 4096000;
    float* P2 = ws + 8192000;
    float* P3 = ws + 12288000;
    unsigned short* SD  = (unsigned short*)(ws + 16384000);  // 2 x 4,096,000 u16
    unsigned short* Zsw = (unsigned short*)(ws + 20480000);  // 2 x 2,048,000 u16
    float* R12 = ws + 22528000;                              // 2 x 51,200 f
    float* A1  = ws + 22630400;                              // 102,400 f
    float* B1  = ws + 22732800;                              // 102,400 f
    unsigned short* WrT = (unsigned short*)(ws + 22835200);  // 131,072 u16
    unsigned short* Bt3 = (unsigned short*)(ws + 22900736);  //  49,152 u16
    unsigned short* W2T = (unsigned short*)(ws + 22925312);  //  16,384 u16

    k_prep<<<152, 256, 0, stream>>>(Wr, Wsv, Wsr2, Wdr2, Wf2, WrT, Bt3, W2T);
    k_atomsSD<<<dim3(NA / 64, 2), 256, 0, stream>>>(atoms0, atoms1, Wsr1, Wdr1, SD);
    k_gemm_big<<<dim3(63, 4, 2), 512, 0, stream>>>(residues0, residues1, WrT, P0);
    k_gather1<<<dim3(NA / 16, 2), 256, 0, stream>>>(P0, P1, P2, P3, SD,
                                                    same0, diff0, same1, diff1,
                                                    atoms0, atoms1, Wv, Zsw);
    k_gemm_l2<<<dim3(NA / 32, 3, 2), 256, 0, stream>>>(Zsw, Bt3, P0, SD);
    k_gather_res<<<dim3(NRES, 2), 256, 0, stream>>>(P0, SD, same0, diff0, same1, diff1, R12);
    k_pairprep<<<NRES, 256, 0, stream>>>(R12, R12 + 51200, Wf1, bf1, A1, B1);
    k_pairs_mfma<<<dim3(25, 25), 256, 0, stream>>>(A1, B1, W2T, bf2, Wf3, bf3, (float*)d_out);
}

// Round 13
// 130.476 us; speedup vs baseline: 1.0994x; 1.0994x over previous
//
#include <hip/hip_runtime.h>
#include <stdint.h>

#define NA   16000
#define KNN  10
#define NRES 400
#define APR  40
#define NCAT 12
#define BERT 1024
#define FF   128
#define DF1  256
#define DF2  64

using short8   = __attribute__((ext_vector_type(8))) short;
using floatx4  = __attribute__((ext_vector_type(4))) float;
using ushort4v = __attribute__((ext_vector_type(4))) unsigned short;
using ushort8v = __attribute__((ext_vector_type(8))) unsigned short;

__device__ __forceinline__ unsigned short bfc(float v) {
    return __builtin_bit_cast(unsigned short, (__bf16)v);
}
__device__ __forceinline__ float bflo(uint32_t u){ return __uint_as_float(u << 16); }
__device__ __forceinline__ float bfhi(uint32_t u){ return __uint_as_float(u & 0xffff0000u); }

// async global->LDS, 16B per lane
__device__ __forceinline__ void gload16(void* lds, const void* g) {
    __builtin_amdgcn_global_load_lds(
        (const __attribute__((address_space(1))) uint32_t*)g,
        (__attribute__((address_space(3))) uint32_t*)lds, 16, 0, 0);
}

// ---------------------------------------------------------------------------
// Weight prep.  WrT: 16 pre-swizzled 128x64 bf16 tiles (linear gload -> LDS
// image already XOR-swizzled); Bt3: 3 mats x 2 tiles; W2T: [64][256] bf16.
// ---------------------------------------------------------------------------
__global__ void k_prep(const float* __restrict__ Wr,
                       const float* __restrict__ Wsv, const float* __restrict__ Wsr2,
                       const float* __restrict__ Wdr2, const float* __restrict__ Wf2,
                       unsigned short* __restrict__ WrT, unsigned short* __restrict__ Bt3,
                       unsigned short* __restrict__ W2T)
{
    int idx = blockIdx.x * 256 + threadIdx.x;
    if (idx < 16384) {
        int t = idx >> 10, rem = idx & 1023, n = rem >> 3, kq = rem & 7;
        ushort8v v;
#pragma unroll
        for (int e = 0; e < 8; ++e)
            v[e] = bfc(Wr[(size_t)(t * 64 + kq * 8 + e) * FF + n]);
        int ba = t * 16384 + ((n * 128 + kq * 16) ^ ((n & 7) << 4));
        *(ushort8v*)((char*)WrT + ba) = v;
    } else if (idx < 16384 + 6144) {
        int i2 = idx - 16384;
        int m = i2 >> 11, r2 = i2 & 2047;
        int t = r2 >> 10, r3 = r2 & 1023, n = r3 >> 3, kq = r3 & 7;
        const float* W = (m == 0) ? Wsv : ((m == 1) ? Wsr2 : Wdr2);
        ushort8v v;
#pragma unroll
        for (int e = 0; e < 8; ++e)
            v[e] = bfc(W[(size_t)(t * 64 + kq * 8 + e) * FF + n]);
        int ba = (m * 2 + t) * 16384 + ((n * 128 + kq * 16) ^ ((n & 7) << 4));
        *(ushort8v*)((char*)Bt3 + ba) = v;
    } else {
        int i3 = idx - 16384 - 6144;
        int n = i3 >> 8, k = i3 & 255;
        W2T[i3] = bfc(Wf2[(size_t)k * DF2 + n]);
    }
}

// ---------------------------------------------------------------------------
// SD[a][0:128]=bf16(atoms@Wsr1), [128:256]=bf16(atoms@Wdr1).
// ---------------------------------------------------------------------------
__global__ void __launch_bounds__(256)
k_atomsSD(const float* __restrict__ atoms0, const float* __restrict__ atoms1,
          const float* __restrict__ Wsr1, const float* __restrict__ Wdr1,
          unsigned short* __restrict__ SD)
{
    __shared__ float sAt[64 * NCAT];   // 3 KB
    const int p = blockIdx.y;
    const float* atoms = p ? atoms1 : atoms0;
    unsigned short* SDp = SD + (size_t)p * 4096000;
    const int a0 = blockIdx.x * 64;
    const int tid = threadIdx.x;
    const int f = tid & 127, half = tid >> 7;

    if (tid < 192)
        ((float4*)sAt)[tid] = *(const float4*)&atoms[(size_t)a0 * NCAT + tid * 4];

    float wsr[NCAT], wdr[NCAT];
#pragma unroll
    for (int c = 0; c < NCAT; ++c) {
        wsr[c] = Wsr1[c * FF + f];
        wdr[c] = Wdr1[c * FF + f];
    }
    __syncthreads();

#pragma unroll 4
    for (int pass = 0; pass < 32; ++pass) {
        int ai = pass * 2 + half;
        int a = a0 + ai;
        float ss = 0.f, sd = 0.f;
#pragma unroll
        for (int c = 0; c < NCAT; ++c) {
            float ac = sAt[ai * NCAT + c];
            ss = fmaf(ac, wsr[c], ss);
            sd = fmaf(ac, wdr[c], sd);
        }
        SDp[(size_t)a * 256 + f]       = bfc(ss);
        SDp[(size_t)a * 256 + 128 + f] = bfc(sd);
    }
}

// ---------------------------------------------------------------------------
// Big GEMM (round-6 champion, 49 us): residues[16000,1024] @ Wr -> ACC fp32.
// BM=64, BK=64, 16 K-tiles, counted-vmcnt 3-stage pipeline, raw s_barrier:
//   per tile t: issue B(t+1) gloads | issue A(t+2) reg loads | MFMA tile t |
//   ds_write A(t+1) | s_waitcnt vmcnt(4) lgkmcnt(0) | s_barrier.
// ---------------------------------------------------------------------------
__global__ void __launch_bounds__(256)
k_gemm_big(const float* __restrict__ R0, const float* __restrict__ R1,
           const unsigned short* __restrict__ Bsw, float* __restrict__ OUT)
{
    __shared__ __align__(16) unsigned short sA[2][64 * 64];    // 2 x 8 KB
    __shared__ __align__(16) unsigned short sB[2][128 * 64];   // 2 x 16 KB
    const int tid = threadIdx.x, l = tid & 63, w = tid >> 6;
    const int m0 = blockIdx.x * 64;
    const float* A = blockIdx.y ? R1 : R0;
    float* C = OUT + (size_t)blockIdx.y * 2048000;

    floatx4 acc[4][2];
#pragma unroll
    for (int mt = 0; mt < 4; ++mt)
#pragma unroll
        for (int nt = 0; nt < 2; ++nt) acc[mt][nt] = (floatx4){0.f, 0.f, 0.f, 0.f};

    const int arow = tid >> 4, acol = (tid & 15) * 4;

    // ---- prologue ----
    {
        float4 a0r[4];
#pragma unroll
        for (int pass = 0; pass < 4; ++pass)
            a0r[pass] = *(const float4*)&A[(size_t)(m0 + pass * 16 + arow) * BERT + acol];
#pragma unroll
        for (int pass = 0; pass < 4; ++pass) {
            int row = pass * 16 + arow;
            ushort4v hv = {bfc(a0r[pass].x), bfc(a0r[pass].y), bfc(a0r[pass].z), bfc(a0r[pass].w)};
            *(ushort4v*)((char*)sA[0] + ((row * 128 + (tid & 15) * 8) ^ ((row & 7) << 4))) = hv;
        }
    }
    __builtin_amdgcn_sched_barrier(0);
    {
        const char* bs = (const char*)Bsw + tid * 16;
        char* bd = (char*)sB[0] + tid * 16;
#pragma unroll
        for (int q = 0; q < 4; ++q) gload16(bd + q * 4096, bs + q * 4096);
    }
    __builtin_amdgcn_sched_barrier(0);
    float4 aP[4], aQ[4];
#pragma unroll
    for (int pass = 0; pass < 4; ++pass)
        aP[pass] = *(const float4*)&A[(size_t)(m0 + pass * 16 + arow) * BERT + 64 + acol];
    __builtin_amdgcn_sched_barrier(0);
    asm volatile("s_waitcnt vmcnt(4) lgkmcnt(0)" ::: "memory");
    __builtin_amdgcn_sched_barrier(0);
    __builtin_amdgcn_s_barrier();
    __builtin_amdgcn_sched_barrier(0);

    // ---- main loop ----
    auto step = [&](int t, int cur, float4* aC, float4* aN) {
        const int nxt = cur ^ 1;
        // issue B(t+1) -> sB[nxt] (clamped dummy at t=15 keeps counts uniform)
        {
            int bt = (t + 1 < 16) ? t + 1 : 15;
            const char* bs = (const char*)Bsw + (size_t)bt * 16384 + tid * 16;
            char* bd = (char*)sB[nxt] + tid * 16;
#pragma unroll
            for (int q = 0; q < 4; ++q) gload16(bd + q * 4096, bs + q * 4096);
        }
        __builtin_amdgcn_sched_barrier(0);
        // issue A(t+2) reg loads (clamped)
        {
            int at2 = (t + 2 < 16) ? t + 2 : 15;
#pragma unroll
            for (int pass = 0; pass < 4; ++pass)
                aN[pass] = *(const float4*)&A[(size_t)(m0 + pass * 16 + arow) * BERT + at2 * 64 + acol];
        }
        __builtin_amdgcn_sched_barrier(0);
        // compute tile t
#pragma unroll
        for (int ks = 0; ks < 2; ++ks) {
            short8 ah[4], bh[2];
            const int kb = ks * 64 + (l >> 4) * 16;
#pragma unroll
            for (int mt = 0; mt < 4; ++mt) {
                int row = mt * 16 + (l & 15);
                ah[mt] = *(const short8*)((char*)sA[cur] + ((row * 128 + kb) ^ ((row & 7) << 4)));
            }
#pragma unroll
            for (int nt = 0; nt < 2; ++nt) {
                int row = w * 32 + nt * 16 + (l & 15);
                bh[nt] = *(const short8*)((char*)sB[cur] + ((row * 128 + kb) ^ ((row & 7) << 4)));
            }
#pragma unroll
            for (int mt = 0; mt < 4; ++mt)
#pragma unroll
                for (int nt = 0; nt < 2; ++nt)
                    acc[mt][nt] = __builtin_amdgcn_mfma_f32_16x16x32_bf16(ah[mt], bh[nt], acc[mt][nt], 0, 0, 0);
        }
        __builtin_amdgcn_sched_barrier(0);
        // ds_write A(t+1) -> sA[nxt] (compiler inserts counted vmcnt for aC)
#pragma unroll
        for (int pass = 0; pass < 4; ++pass) {
            int row = pass * 16 + arow;
            ushort4v hv = {bfc(aC[pass].x), bfc(aC[pass].y), bfc(aC[pass].z), bfc(aC[pass].w)};
            *(ushort4v*)((char*)sA[nxt] + ((row * 128 + (tid & 15) * 8) ^ ((row & 7) << 4))) = hv;
        }
        __builtin_amdgcn_sched_barrier(0);
        asm volatile("s_waitcnt vmcnt(4) lgkmcnt(0)" ::: "memory");
        __builtin_amdgcn_sched_barrier(0);
        __builtin_amdgcn_s_barrier();
        __builtin_amdgcn_sched_barrier(0);
    };
#pragma unroll
    for (int tt = 0; tt < 8; ++tt) {
        step(2 * tt,     0, aP, aQ);
        step(2 * tt + 1, 1, aQ, aP);
    }

    // ---- epilogue ----
#pragma unroll
    for (int mt = 0; mt < 4; ++mt)
#pragma unroll
        for (int nt = 0; nt < 2; ++nt)
#pragma unroll
            for (int r = 0; r < 4; ++r) {
                int row = m0 + mt * 16 + (l >> 4) * 4 + r;
                int col = w * 32 + nt * 16 + (l & 15);
                C[(size_t)row * FF + col] = acc[mt][nt][r];
            }
}

// ---------------------------------------------------------------------------
// Layer-2 GEMM: Z(pre-swizzled bf16 tiles) @ {Wsv,Wsr2,Wdr2}.
// ---------------------------------------------------------------------------
__global__ void __launch_bounds__(256)
k_gemm_l2(const unsigned short* __restrict__ Zsw, const unsigned short* __restrict__ Bt3,
          float* __restrict__ ACC, unsigned short* __restrict__ SD)
{
    __shared__ __align__(16) unsigned short sA[2][32 * 64];   // 2 x 4 KB
    __shared__ __align__(16) unsigned short sB[2][128 * 64];  // 2 x 16 KB
    const int tid = threadIdx.x, l = tid & 63, w = tid >> 6;
    const int m0 = blockIdx.x * 32;
    const int mat = blockIdx.y, p = blockIdx.z;
    const unsigned short* Zp = Zsw + (size_t)p * 2048000;

    floatx4 acc[2][2];
#pragma unroll
    for (int mt = 0; mt < 2; ++mt)
#pragma unroll
        for (int nt = 0; nt < 2; ++nt) acc[mt][nt] = (floatx4){0.f, 0.f, 0.f, 0.f};

#pragma unroll
    for (int t = 0; t < 2; ++t) {
        const char* bs = (const char*)Bt3 + (size_t)(mat * 2 + t) * 16384 + tid * 16;
#pragma unroll
        for (int q = 0; q < 4; ++q) gload16((char*)sB[t] + tid * 16 + q * 4096, bs + q * 4096);
        gload16((char*)sA[t] + tid * 16,
                (const char*)Zp + (size_t)((m0 >> 5) * 2 + t) * 4096 + tid * 16);
    }
    __syncthreads();

#pragma unroll
    for (int t = 0; t < 2; ++t)
#pragma unroll
        for (int ks = 0; ks < 2; ++ks) {
            short8 ah[2], bh[2];
            const int kb = ks * 64 + (l >> 4) * 16;
#pragma unroll
            for (int mt = 0; mt < 2; ++mt) {
                int row = mt * 16 + (l & 15);
                ah[mt] = *(const short8*)((char*)sA[t] + ((row * 128 + kb) ^ ((row & 7) << 4)));
            }
#pragma unroll
            for (int nt = 0; nt < 2; ++nt) {
                int row = w * 32 + nt * 16 + (l & 15);
                bh[nt] = *(const short8*)((char*)sB[t] + ((row * 128 + kb) ^ ((row & 7) << 4)));
            }
#pragma unroll
            for (int mt = 0; mt < 2; ++mt)
#pragma unroll
                for (int nt = 0; nt < 2; ++nt)
                    acc[mt][nt] = __builtin_amdgcn_mfma_f32_16x16x32_bf16(ah[mt], bh[nt], acc[mt][nt], 0, 0, 0);
        }

    float* ACCp = ACC + (size_t)p * 2048000;
    unsigned short* SDp = (unsigned short*)SD + (size_t)p * 4096000;
#pragma unroll
    for (int mt = 0; mt < 2; ++mt)
#pragma unroll
        for (int nt = 0; nt < 2; ++nt)
#pragma unroll
            for (int r = 0; r < 4; ++r) {
                int row = m0 + mt * 16 + (l >> 4) * 4 + r;
                int col = w * 32 + nt * 16 + (l & 15);
                float v = acc[mt][nt][r];
                if (mat == 0) ACCp[(size_t)row * FF + col] = v;
                else          SDp [(size_t)row * 256 + (mat - 1) * FF + col] = bfc(v);
            }
}

// ---------------------------------------------------------------------------
// Gather 1: Z = relu(ACC + atoms@Wv + mean(S,sn) + mean(D,dn)) -> Zsw
// (bf16, pre-swizzled tiles for k_gemm_l2's A staging).
// ---------------------------------------------------------------------------
__global__ void __launch_bounds__(256)
k_gather1(const float* __restrict__ ACC, const unsigned short* __restrict__ SD,
          const int* __restrict__ sn0, const int* __restrict__ dn0,
          const int* __restrict__ sn1, const int* __restrict__ dn1,
          const float* __restrict__ atoms0, const float* __restrict__ atoms1,
          const float* __restrict__ Wv, unsigned short* __restrict__ Zout)
{
    __shared__ int sIdx[16][20];
    __shared__ float sWv[NCAT * FF];   // 6 KB
    __shared__ float sAt[16 * NCAT];   // 768 B
    const int tid = threadIdx.x;
    const int p = blockIdx.y;
    const int a0 = blockIdx.x * 16;
    const int* sn = p ? sn1 : sn0;
    const int* dn = p ? dn1 : dn0;
    const float* ACCp = ACC + (size_t)p * 2048000;
    const unsigned short* SDp = SD + (size_t)p * 4096000;
    unsigned short* Zp = Zout + (size_t)p * 2048000;

    for (int t = tid; t < 320; t += 256) {
        int at = t / 20, q = t - at * 20;
        sIdx[at][q] = (q < 10) ? sn[(a0 + at) * KNN + q] : dn[(a0 + at) * KNN + q - 10];
    }
    {
        const float* atoms = p ? atoms1 : atoms0;
        for (int i = tid; i < 384; i += 256)
            ((float4*)sWv)[i] = ((const float4*)Wv)[i];
        if (tid < 48) {
            int at = tid / 3, q = tid - at * 3;
            *(float4*)&sAt[at * NCAT + q * 4] =
                *(const float4*)&atoms[(size_t)(a0 + at) * NCAT + q * 4];
        }
    }
    __syncthreads();
    const int at = tid >> 4, c8 = tid & 15;
    const int a = a0 + at;
    float ss[8] = {0,0,0,0,0,0,0,0}, dd[8] = {0,0,0,0,0,0,0,0};
    int sc = 0, dc = 0;
#pragma unroll
    for (int n = 0; n < KNN; ++n) {
        int is = sIdx[at][n];
        if (is > -1) {
            sc++;
            uint4 v = *(const uint4*)&SDp[(size_t)is * 256 + c8 * 8];
            uint32_t vv[4] = {v.x, v.y, v.z, v.w};
#pragma unroll
            for (int q = 0; q < 4; ++q) { ss[2*q] += bflo(vv[q]); ss[2*q+1] += bfhi(vv[q]); }
        }
    }
#pragma unroll
    for (int n = 0; n < KNN; ++n) {
        int id = sIdx[at][10 + n];
        if (id > -1) {
            dc++;
            uint4 v = *(const uint4*)&SDp[(size_t)id * 256 + 128 + c8 * 8];
            uint32_t vv[4] = {v.x, v.y, v.z, v.w};
#pragma unroll
            for (int q = 0; q < 4; ++q) { dd[2*q] += bflo(vv[q]); dd[2*q+1] += bfhi(vv[q]); }
        }
    }
    const float rs = 1.f / (sc > 0 ? (float)sc : 1.f);
    const float rd = 1.f / (dc > 0 ? (float)dc : 1.f);
    float4 a0v = *(const float4*)&ACCp[(size_t)a * FF + c8 * 8];
    float4 a1v = *(const float4*)&ACCp[(size_t)a * FF + c8 * 8 + 4];
    float ov[8] = {a0v.x, a0v.y, a0v.z, a0v.w, a1v.x, a1v.y, a1v.z, a1v.w};
#pragma unroll
    for (int c = 0; c < NCAT; ++c) {
        float ac = sAt[at * NCAT + c];
        float4 w0 = *(const float4*)&sWv[c * FF + c8 * 8];
        float4 w1 = *(const float4*)&sWv[c * FF + c8 * 8 + 4];
        ov[0] = fmaf(ac, w0.x, ov[0]); ov[1] = fmaf(ac, w0.y, ov[1]);
        ov[2] = fmaf(ac, w0.z, ov[2]); ov[3] = fmaf(ac, w0.w, ov[3]);
        ov[4] = fmaf(ac, w1.x, ov[4]); ov[5] = fmaf(ac, w1.y, ov[5]);
        ov[6] = fmaf(ac, w1.z, ov[6]); ov[7] = fmaf(ac, w1.w, ov[7]);
    }
    ushort8v zv;
#pragma unroll
    for (int e = 0; e < 8; ++e)
        zv[e] = bfc(fmaxf(fmaf(ss[e], rs, fmaf(dd[e], rd, ov[e])), 0.f));
    int ba = ((a >> 5) * 2 + (c8 >> 3)) * 4096
           + (((a & 31) * 128 + (c8 & 7) * 16) ^ ((a & 7) << 4));
    *(ushort8v*)((char*)Zp + ba) = zv;
}

// ---------------------------------------------------------------------------
// Gather 2 fused with residue mean: one block per residue (40 atoms).
// ---------------------------------------------------------------------------
__global__ void __launch_bounds__(256)
k_gather_res(const float* __restrict__ ACC, const unsigned short* __restrict__ SD,
             const int* __restrict__ sn0, const int* __restrict__ dn0,
             const int* __restrict__ sn1, const int* __restrict__ dn1,
             float* __restrict__ R12)
{
    __shared__ int sIdx[APR][20];      // 3.2 KB
    __shared__ float zpart[16][128];   // 8 KB
    const int tid = threadIdx.x;
    const int p = blockIdx.y, r = blockIdx.x;
    const int* sn = p ? sn1 : sn0;
    const int* dn = p ? dn1 : dn0;
    const float* ACCp = ACC + (size_t)p * 2048000;
    const unsigned short* SDp = SD + (size_t)p * 4096000;
    const int aBase = r * APR;

    for (int t = tid; t < APR * 20; t += 256) {
        int at = t / 20, q = t - at * 20;
        sIdx[at][q] = (q < 10) ? sn[(aBase + at) * KNN + q] : dn[(aBase + at) * KNN + q - 10];
    }
    __syncthreads();

    const int at = tid >> 4, c8 = tid & 15;
    float zs[8] = {0,0,0,0,0,0,0,0};
#pragma unroll
    for (int rep = 0; rep < 3; ++rep) {
        int ai = at + rep * 16;
        if (ai < APR) {
            int a = aBase + ai;
            float ss[8] = {0,0,0,0,0,0,0,0}, dd[8] = {0,0,0,0,0,0,0,0};
            int sc = 0, dc = 0;
#pragma unroll
            for (int n = 0; n < KNN; ++n) {
                int is = sIdx[ai][n];
                if (is > -1) {
                    sc++;
                    uint4 v = *(const uint4*)&SDp[(size_t)is * 256 + c8 * 8];
                    uint32_t vv[4] = {v.x, v.y, v.z, v.w};
#pragma unroll
                    for (int q = 0; q < 4; ++q) { ss[2*q] += bflo(vv[q]); ss[2*q+1] += bfhi(vv[q]); }
                }
            }
#pragma unroll
            for (int n = 0; n < KNN; ++n) {
                int id = sIdx[ai][10 + n];
                if (id > -1) {
                    dc++;
                    uint4 v = *(const uint4*)&SDp[(size_t)id * 256 + 128 + c8 * 8];
                    uint32_t vv[4] = {v.x, v.y, v.z, v.w};
#pragma unroll
                    for (int q = 0; q < 4; ++q) { dd[2*q] += bflo(vv[q]); dd[2*q+1] += bfhi(vv[q]); }
                }
            }
            const float rs = 1.f / (sc > 0 ? (float)sc : 1.f);
            const float rd = 1.f / (dc > 0 ? (float)dc : 1.f);
            float4 a0v = *(const float4*)&ACCp[(size_t)a * FF + c8 * 8];
            float4 a1v = *(const float4*)&ACCp[(size_t)a * FF + c8 * 8 + 4];
            float ov[8] = {a0v.x, a0v.y, a0v.z, a0v.w, a1v.x, a1v.y, a1v.z, a1v.w};
#pragma unroll
            for (int e = 0; e < 8; ++e)
                zs[e] += fmaxf(fmaf(ss[e], rs, fmaf(dd[e], rd, ov[e])), 0.f);
        }
    }
    *(float4*)&zpart[at][c8 * 8]     = (float4){zs[0], zs[1], zs[2], zs[3]};
    *(float4*)&zpart[at][c8 * 8 + 4] = (float4){zs[4], zs[5], zs[6], zs[7]};
    __syncthreads();
#pragma unroll
    for (int s = 8; s > 0; s >>= 1) {
        if (at < s) {
            float4 x0 = *(const float4*)&zpart[at + s][c8 * 8];
            float4 x1 = *(const float4*)&zpart[at + s][c8 * 8 + 4];
            float4 y0 = *(const float4*)&zpart[at][c8 * 8];
            float4 y1 = *(const float4*)&zpart[at][c8 * 8 + 4];
            y0.x += x0.x; y0.y += x0.y; y0.z += x0.z; y0.w += x0.w;
            y1.x += x1.x; y1.y += x1.y; y1.z += x1.z; y1.w += x1.w;
            *(float4*)&zpart[at][c8 * 8]     = y0;
            *(float4*)&zpart[at][c8 * 8 + 4] = y1;
        }
        __syncthreads();
    }
    if (at == 0) {
        float* R = R12 + (size_t)p * 51200 + (size_t)r * FF;
        const float inv = 1.0f / APR;
#pragma unroll
        for (int e = 0; e < 8; ++e) R[c8 * 8 + e] = zpart[0][c8 * 8 + e] * inv;
    }
}

// ---------------------------------------------------------------------------
// A1[i] = r1[i] @ Wf1[:128,:] + bf1 ;  B1[j] = r2[j] @ Wf1[128:,:]
// ---------------------------------------------------------------------------
__global__ void k_pairprep(const float* __restrict__ R1, const float* __restrict__ R2,
                           const float* __restrict__ Wf1, const float* __restrict__ bf1,
                           float* __restrict__ A1, float* __restrict__ B1)
{
    __shared__ float r1s[FF], r2s[FF];
    int i = blockIdx.x, o = threadIdx.x;   // 256 threads
    if (o < FF) r1s[o] = R1[i * FF + o];
    else        r2s[o - FF] = R2[i * FF + (o - FF)];
    __syncthreads();
    float sa = bf1[o], sb = 0.f;
#pragma unroll 8
    for (int k = 0; k < FF; ++k) {
        sa = fmaf(r1s[k], Wf1[(size_t)k * DF1 + o], sa);
        sb = fmaf(r2s[k], Wf1[(size_t)(FF + k) * DF1 + o], sb);
    }
    A1[(size_t)i * DF1 + o] = sa;
    B1[(size_t)i * DF1 + o] = sb;
}

// ---------------------------------------------------------------------------
// Pair MLP via MFMA, register-built H.
// ---------------------------------------------------------------------------
__global__ void __launch_bounds__(256)
k_pairs_mfma(const float* __restrict__ A1, const float* __restrict__ B1,
             const unsigned short* __restrict__ W2T,
             const float* __restrict__ bf2, const float* __restrict__ Wf3,
             const float* __restrict__ bf3, float* __restrict__ out)
{
    __shared__ __align__(16) float sA1[16 * 256];            // 16 KB linear
    __shared__ __align__(16) float sB1[16 * 256];            // 16 KB, XOR (row&7)<<5
    __shared__ __align__(16) unsigned short sW[64 * 256];    // 32 KB, XOR (n&7)<<4
    const int tid = threadIdx.x, l = tid & 63, w = tid >> 6;
    const int i0 = blockIdx.x * 16, j0 = blockIdx.y * 16;

    for (int idx = tid; idx < 64 * 32; idx += 256) {
        int row = idx >> 5, c = idx & 31;
        int ba = (row * 512 + c * 16) ^ ((row & 7) << 4);
        *(uint4*)((char*)sW + ba) = *(const uint4*)(W2T + row * 256 + c * 8);
    }
    {
        int row = tid >> 4;
#pragma unroll
        for (int pass = 0; pass < 4; ++pass) {
            int coff = pass * 64 + (tid & 15) * 4;
            *(float4*)((char*)sA1 + row * 1024 + coff * 4) =
                *(const float4*)&A1[(size_t)(i0 + row) * DF1 + coff];
            int bb = (row * 1024 + coff * 4) ^ ((row & 7) << 5);
            *(float4*)((char*)sB1 + bb) =
                *(const float4*)&B1[(size_t)(j0 + row) * DF1 + coff];
        }
    }
    __syncthreads();

    floatx4 acc[4][4];
#pragma unroll
    for (int mt = 0; mt < 4; ++mt)
#pragma unroll
        for (int nt = 0; nt < 4; ++nt) acc[mt][nt] = (floatx4){0.f, 0.f, 0.f, 0.f};

    float b2r[4], w3r[4];
#pragma unroll
    for (int nt = 0; nt < 4; ++nt) {
        b2r[nt] = bf2[nt * 16 + (l & 15)];
        w3r[nt] = Wf3[nt * 16 + (l & 15)];
    }

    const int rB = l & 15, kq = l >> 4;
#pragma unroll
    for (int kc = 0; kc < 4; ++kc)
#pragma unroll
        for (int ks = 0; ks < 2; ++ks) {
            const int kfb = (kc * 64 + ks * 32 + kq * 8) * 4;
            float4 b1a = *(const float4*)((char*)sB1 + ((rB * 1024 + kfb)      ^ ((rB & 7) << 5)));
            float4 b1b = *(const float4*)((char*)sB1 + ((rB * 1024 + kfb + 16) ^ ((rB & 7) << 5)));
            short8 afr[4];
#pragma unroll
            for (int mt = 0; mt < 4; ++mt) {
                int rA = w * 4 + mt;
                float4 a1a = *(const float4*)((char*)sA1 + rA * 1024 + kfb);
                float4 a1b = *(const float4*)((char*)sA1 + rA * 1024 + kfb + 16);
                short8 hv;
                hv[0] = (short)bfc(fmaxf(a1a.x + b1a.x, 0.f));
                hv[1] = (short)bfc(fmaxf(a1a.y + b1a.y, 0.f));
                hv[2] = (short)bfc(fmaxf(a1a.z + b1a.z, 0.f));
                hv[3] = (short)bfc(fmaxf(a1a.w + b1a.w, 0.f));
                hv[4] = (short)bfc(fmaxf(a1b.x + b1b.x, 0.f));
                hv[5] = (short)bfc(fmaxf(a1b.y + b1b.y, 0.f));
                hv[6] = (short)bfc(fmaxf(a1b.z + b1b.z, 0.f));
                hv[7] = (short)bfc(fmaxf(a1b.w + b1b.w, 0.f));
                afr[mt] = hv;
            }
            const int kwb = kc * 128 + ks * 64 + kq * 16;
            short8 bfr[4];
#pragma unroll
            for (int nt = 0; nt < 4; ++nt) {
                int n = nt * 16 + (l & 15);
                bfr[nt] = *(const short8*)((char*)sW + ((n * 512 + kwb) ^ ((n & 7) << 4)));
            }
#pragma unroll
            for (int mt = 0; mt < 4; ++mt)
#pragma unroll
                for (int nt = 0; nt < 4; ++nt)
                    acc[mt][nt] = __builtin_amdgcn_mfma_f32_16x16x32_bf16(afr[mt], bfr[nt], acc[mt][nt], 0, 0, 0);
        }

    const float b3 = bf3[0];
#pragma unroll
    for (int mt = 0; mt < 4; ++mt)
#pragma unroll
        for (int r = 0; r < 4; ++r) {
            float s = 0.f;
#pragma unroll
            for (int nt = 0; nt < 4; ++nt)
                s += fmaxf(acc[mt][nt][r] + b2r[nt], 0.f) * w3r[nt];
            s += __shfl_xor(s, 1); s += __shfl_xor(s, 2);
            s += __shfl_xor(s, 4); s += __shfl_xor(s, 8);
            if ((l & 15) == 0) {
                int p = w * 64 + mt * 16 + (l >> 4) * 4 + r;
                out[(size_t)(i0 + (p >> 4)) * NRES + j0 + (p & 15)] = s + b3;
            }
        }
}

// ---------------------------------------------------------------------------
extern "C" void kernel_launch(void* const* d_in, const int* in_sizes, int n_in,
                              void* d_out, int out_size, void* d_ws, size_t ws_size,
                              hipStream_t stream)
{
    const float* atoms0    = (const float*)d_in[0];
    const float* residues0 = (const float*)d_in[1];
    const int*   same0     = (const int*)d_in[2];
    const int*   diff0     = (const int*)d_in[3];
    const float* atoms1    = (const float*)d_in[5];
    const float* residues1 = (const float*)d_in[6];
    const int*   same1     = (const int*)d_in[7];
    const int*   diff1     = (const int*)d_in[8];
    const float* Wv   = (const float*)d_in[10];
    const float* Wr   = (const float*)d_in[11];
    const float* Wsr1 = (const float*)d_in[12];
    const float* Wdr1 = (const float*)d_in[13];
    const float* Wsv  = (const float*)d_in[14];
    const float* Wsr2 = (const float*)d_in[15];
    const float* Wdr2 = (const float*)d_in[16];
    const float* Wf1  = (const float*)d_in[17];
    const float* bf1  = (const float*)d_in[18];
    const float* Wf2  = (const float*)d_in[19];
    const float* bf2  = (const float*)d_in[20];
    const float* Wf3  = (const float*)d_in[21];
    const float* bf3  = (const float*)d_in[22];

    float* ws  = (float*)d_ws;
    float* ACC = ws;                                         // 2 x 2,048,000 f
    unsigned short* SD  = (unsigned short*)(ws + 4096000);   // 2 x 4,096,000 u16
    unsigned short* Zsw = (unsigned short*)(ws + 8192000);   // 2 x 2,048,000 u16
    float* R12 = ws + 10240000;                              // 2 x 51,200 f
    float* A1  = ws + 10342400;                              // 102,400 f
    float* B1  = ws + 10444800;                              // 102,400 f
    unsigned short* WrT = (unsigned short*)(ws + 10547200);  // 131,072 u16
    unsigned short* Bt3 = (unsigned short*)(ws + 10612736);  //  49,152 u16
    unsigned short* W2T = (unsigned short*)(ws + 10637312);  //  16,384 u16

    k_prep<<<152, 256, 0, stream>>>(Wr, Wsv, Wsr2, Wdr2, Wf2, WrT, Bt3, W2T);
    k_atomsSD<<<dim3(NA / 64, 2), 256, 0, stream>>>(atoms0, atoms1, Wsr1, Wdr1, SD);
    k_gemm_big<<<dim3(NA / 64, 2), 256, 0, stream>>>(residues0, residues1, WrT, ACC);
    k_gather1<<<dim3(NA / 16, 2), 256, 0, stream>>>(ACC, SD, same0, diff0, same1, diff1,
                                                    atoms0, atoms1, Wv, Zsw);
    k_gemm_l2<<<dim3(NA / 32, 3, 2), 256, 0, stream>>>(Zsw, Bt3, ACC, SD);
    k_gather_res<<<dim3(NRES, 2), 256, 0, stream>>>(ACC, SD, same0, diff0, same1, diff1, R12);
    k_pairprep<<<NRES, 256, 0, stream>>>(R12, R12 + 51200, Wf1, bf1, A1, B1);
    k_pairs_mfma<<<dim3(25, 25), 256, 0, stream>>>(A1, B1, W2T, bf2, Wf3, bf3, (float*)d_out);
}

// Round 14
// 123.487 us; speedup vs baseline: 1.1617x; 1.0566x over previous
//
#include <hip/hip_runtime.h>
#include <stdint.h>

#define NA   16000
#define KNN  10
#define NRES 400
#define APR  40
#define NCAT 12
#define BERT 1024
#define FF   128
#define DF1  256
#define DF2  64

using short8   = __attribute__((ext_vector_type(8))) short;
using floatx4  = __attribute__((ext_vector_type(4))) float;
using ushort4v = __attribute__((ext_vector_type(4))) unsigned short;
using ushort8v = __attribute__((ext_vector_type(8))) unsigned short;

__device__ __forceinline__ unsigned short bfc(float v) {
    return __builtin_bit_cast(unsigned short, (__bf16)v);
}
__device__ __forceinline__ float bflo(uint32_t u){ return __uint_as_float(u << 16); }
__device__ __forceinline__ float bfhi(uint32_t u){ return __uint_as_float(u & 0xffff0000u); }

// async global->LDS, 16B per lane
__device__ __forceinline__ void gload16(void* lds, const void* g) {
    __builtin_amdgcn_global_load_lds(
        (const __attribute__((address_space(1))) uint32_t*)g,
        (__attribute__((address_space(3))) uint32_t*)lds, 16, 0, 0);
}

// ---------------------------------------------------------------------------
// Weight prep.  WrT: 16 pre-swizzled 128x64 bf16 tiles; Bt3: 3 mats x 2
// tiles; W2T: [64][256] bf16.
// ---------------------------------------------------------------------------
__global__ void k_prep(const float* __restrict__ Wr,
                       const float* __restrict__ Wsv, const float* __restrict__ Wsr2,
                       const float* __restrict__ Wdr2, const float* __restrict__ Wf2,
                       unsigned short* __restrict__ WrT, unsigned short* __restrict__ Bt3,
                       unsigned short* __restrict__ W2T)
{
    int idx = blockIdx.x * 256 + threadIdx.x;
    if (idx < 16384) {
        int t = idx >> 10, rem = idx & 1023, n = rem >> 3, kq = rem & 7;
        ushort8v v;
#pragma unroll
        for (int e = 0; e < 8; ++e)
            v[e] = bfc(Wr[(size_t)(t * 64 + kq * 8 + e) * FF + n]);
        int ba = t * 16384 + ((n * 128 + kq * 16) ^ ((n & 7) << 4));
        *(ushort8v*)((char*)WrT + ba) = v;
    } else if (idx < 16384 + 6144) {
        int i2 = idx - 16384;
        int m = i2 >> 11, r2 = i2 & 2047;
        int t = r2 >> 10, r3 = r2 & 1023, n = r3 >> 3, kq = r3 & 7;
        const float* W = (m == 0) ? Wsv : ((m == 1) ? Wsr2 : Wdr2);
        ushort8v v;
#pragma unroll
        for (int e = 0; e < 8; ++e)
            v[e] = bfc(W[(size_t)(t * 64 + kq * 8 + e) * FF + n]);
        int ba = (m * 2 + t) * 16384 + ((n * 128 + kq * 16) ^ ((n & 7) << 4));
        *(ushort8v*)((char*)Bt3 + ba) = v;
    } else {
        int i3 = idx - 16384 - 6144;
        int n = i3 >> 8, k = i3 & 255;
        W2T[i3] = bfc(Wf2[(size_t)k * DF2 + n]);
    }
}

// ---------------------------------------------------------------------------
// MEGA 1: blockIdx.x < 250 -> big-GEMM role (counted-vmcnt champion);
//         blockIdx.x >= 250 -> atomsSD role (independent work, rides along).
// GEMM: residues[16000,1024] @ Wr -> ACC fp32.  BM=64, BK=64, 16 K-tiles.
// atomsSD: SD[a][0:128]=bf16(atoms@Wsr1), [128:256]=bf16(atoms@Wdr1).
// ---------------------------------------------------------------------------
__global__ void __launch_bounds__(256)
k_mega1(const float* __restrict__ R0, const float* __restrict__ R1,
        const unsigned short* __restrict__ Bsw,
        const float* __restrict__ atoms0, const float* __restrict__ atoms1,
        const float* __restrict__ Wsr1, const float* __restrict__ Wdr1,
        float* __restrict__ OUT, unsigned short* __restrict__ SD)
{
    __shared__ __align__(16) unsigned short sA[2][64 * 64];    // 2 x 8 KB
    __shared__ __align__(16) unsigned short sB[2][128 * 64];   // 2 x 16 KB
    const int tid = threadIdx.x;

    if (blockIdx.x >= 250) {
        // ---------------- atomsSD role ----------------
        float* sAt = (float*)sA;   // 3 KB carved from sA
        const int p = blockIdx.y;
        const float* atoms = p ? atoms1 : atoms0;
        unsigned short* SDp = SD + (size_t)p * 4096000;
        const int a0 = (blockIdx.x - 250) * 64;
        const int f = tid & 127, half = tid >> 7;

        if (tid < 192)
            ((float4*)sAt)[tid] = *(const float4*)&atoms[(size_t)a0 * NCAT + tid * 4];

        float wsr[NCAT], wdr[NCAT];
#pragma unroll
        for (int c = 0; c < NCAT; ++c) {
            wsr[c] = Wsr1[c * FF + f];
            wdr[c] = Wdr1[c * FF + f];
        }
        __syncthreads();

#pragma unroll 4
        for (int pass = 0; pass < 32; ++pass) {
            int ai = pass * 2 + half;
            int a = a0 + ai;
            float ss = 0.f, sd = 0.f;
#pragma unroll
            for (int c = 0; c < NCAT; ++c) {
                float ac = sAt[ai * NCAT + c];
                ss = fmaf(ac, wsr[c], ss);
                sd = fmaf(ac, wdr[c], sd);
            }
            SDp[(size_t)a * 256 + f]       = bfc(ss);
            SDp[(size_t)a * 256 + 128 + f] = bfc(sd);
        }
        return;
    }

    // ---------------- GEMM role (champion verbatim) ----------------
    const int l = tid & 63, w = tid >> 6;
    const int m0 = blockIdx.x * 64;
    const float* A = blockIdx.y ? R1 : R0;
    float* C = OUT + (size_t)blockIdx.y * 2048000;

    floatx4 acc[4][2];
#pragma unroll
    for (int mt = 0; mt < 4; ++mt)
#pragma unroll
        for (int nt = 0; nt < 2; ++nt) acc[mt][nt] = (floatx4){0.f, 0.f, 0.f, 0.f};

    const int arow = tid >> 4, acol = (tid & 15) * 4;

    // ---- prologue ----
    {
        float4 a0r[4];
#pragma unroll
        for (int pass = 0; pass < 4; ++pass)
            a0r[pass] = *(const float4*)&A[(size_t)(m0 + pass * 16 + arow) * BERT + acol];
#pragma unroll
        for (int pass = 0; pass < 4; ++pass) {
            int row = pass * 16 + arow;
            ushort4v hv = {bfc(a0r[pass].x), bfc(a0r[pass].y), bfc(a0r[pass].z), bfc(a0r[pass].w)};
            *(ushort4v*)((char*)sA[0] + ((row * 128 + (tid & 15) * 8) ^ ((row & 7) << 4))) = hv;
        }
    }
    __builtin_amdgcn_sched_barrier(0);
    {
        const char* bs = (const char*)Bsw + tid * 16;
        char* bd = (char*)sB[0] + tid * 16;
#pragma unroll
        for (int q = 0; q < 4; ++q) gload16(bd + q * 4096, bs + q * 4096);
    }
    __builtin_amdgcn_sched_barrier(0);
    float4 aP[4], aQ[4];
#pragma unroll
    for (int pass = 0; pass < 4; ++pass)
        aP[pass] = *(const float4*)&A[(size_t)(m0 + pass * 16 + arow) * BERT + 64 + acol];
    __builtin_amdgcn_sched_barrier(0);
    asm volatile("s_waitcnt vmcnt(4) lgkmcnt(0)" ::: "memory");
    __builtin_amdgcn_sched_barrier(0);
    __builtin_amdgcn_s_barrier();
    __builtin_amdgcn_sched_barrier(0);

    auto step = [&](int t, int cur, float4* aC, float4* aN) {
        const int nxt = cur ^ 1;
        {
            int bt = (t + 1 < 16) ? t + 1 : 15;
            const char* bs = (const char*)Bsw + (size_t)bt * 16384 + tid * 16;
            char* bd = (char*)sB[nxt] + tid * 16;
#pragma unroll
            for (int q = 0; q < 4; ++q) gload16(bd + q * 4096, bs + q * 4096);
        }
        __builtin_amdgcn_sched_barrier(0);
        {
            int at2 = (t + 2 < 16) ? t + 2 : 15;
#pragma unroll
            for (int pass = 0; pass < 4; ++pass)
                aN[pass] = *(const float4*)&A[(size_t)(m0 + pass * 16 + arow) * BERT + at2 * 64 + acol];
        }
        __builtin_amdgcn_sched_barrier(0);
#pragma unroll
        for (int ks = 0; ks < 2; ++ks) {
            short8 ah[4], bh[2];
            const int kb = ks * 64 + (l >> 4) * 16;
#pragma unroll
            for (int mt = 0; mt < 4; ++mt) {
                int row = mt * 16 + (l & 15);
                ah[mt] = *(const short8*)((char*)sA[cur] + ((row * 128 + kb) ^ ((row & 7) << 4)));
            }
#pragma unroll
            for (int nt = 0; nt < 2; ++nt) {
                int row = w * 32 + nt * 16 + (l & 15);
                bh[nt] = *(const short8*)((char*)sB[cur] + ((row * 128 + kb) ^ ((row & 7) << 4)));
            }
#pragma unroll
            for (int mt = 0; mt < 4; ++mt)
#pragma unroll
                for (int nt = 0; nt < 2; ++nt)
                    acc[mt][nt] = __builtin_amdgcn_mfma_f32_16x16x32_bf16(ah[mt], bh[nt], acc[mt][nt], 0, 0, 0);
        }
        __builtin_amdgcn_sched_barrier(0);
#pragma unroll
        for (int pass = 0; pass < 4; ++pass) {
            int row = pass * 16 + arow;
            ushort4v hv = {bfc(aC[pass].x), bfc(aC[pass].y), bfc(aC[pass].z), bfc(aC[pass].w)};
            *(ushort4v*)((char*)sA[nxt] + ((row * 128 + (tid & 15) * 8) ^ ((row & 7) << 4))) = hv;
        }
        __builtin_amdgcn_sched_barrier(0);
        asm volatile("s_waitcnt vmcnt(4) lgkmcnt(0)" ::: "memory");
        __builtin_amdgcn_sched_barrier(0);
        __builtin_amdgcn_s_barrier();
        __builtin_amdgcn_sched_barrier(0);
    };
#pragma unroll
    for (int tt = 0; tt < 8; ++tt) {
        step(2 * tt,     0, aP, aQ);
        step(2 * tt + 1, 1, aQ, aP);
    }

#pragma unroll
    for (int mt = 0; mt < 4; ++mt)
#pragma unroll
        for (int nt = 0; nt < 2; ++nt)
#pragma unroll
            for (int r = 0; r < 4; ++r) {
                int row = m0 + mt * 16 + (l >> 4) * 4 + r;
                int col = w * 32 + nt * 16 + (l & 15);
                C[(size_t)row * FF + col] = acc[mt][nt][r];
            }
}

// ---------------------------------------------------------------------------
// FUSED gather1 + layer-2 GEMM.  Block = 32 atoms (m0), protein p.
// Phase A: Z rows built in LDS (bf16, swizzled) = relu(ACC + atoms@Wv +
//          mean(S,sn) + mean(D,dn)).  Phase B: Z @ {Wsv,Wsr2,Wdr2} with B
//          staged per-mat via gload; mat0 -> ACC (in-place, row-local),
//          mat1/2 -> SD2 bf16 (separate buffer: SD is still being read
//          randomly by other blocks' phase A).
// ---------------------------------------------------------------------------
__global__ void __launch_bounds__(256)
k_gl2(float* __restrict__ ACC, const unsigned short* __restrict__ SD,
      const unsigned short* __restrict__ Bt3,
      const int* __restrict__ sn0, const int* __restrict__ dn0,
      const int* __restrict__ sn1, const int* __restrict__ dn1,
      const float* __restrict__ atoms0, const float* __restrict__ atoms1,
      const float* __restrict__ Wv, unsigned short* __restrict__ SD2)
{
    __shared__ int sIdx[32][20];                         // 2.5 KB
    __shared__ float sWv[NCAT * FF];                     // 6 KB
    __shared__ float sAt[32 * NCAT];                     // 1.5 KB
    __shared__ __align__(16) unsigned short sZ[32 * 128];     // 8 KB swizzled
    __shared__ __align__(16) unsigned short sB[2][128 * 64];  // 32 KB
    const int tid = threadIdx.x, l = tid & 63, w = tid >> 6;
    const int p = blockIdx.y, m0 = blockIdx.x * 32;
    const int* sn = p ? sn1 : sn0;
    const int* dn = p ? dn1 : dn0;
    float* ACCp = ACC + (size_t)p * 2048000;
    const unsigned short* SDp = SD + (size_t)p * 4096000;
    unsigned short* SD2p = SD2 + (size_t)p * 4096000;

    for (int t = tid; t < 640; t += 256) {
        int at = t / 20, q = t - at * 20;
        sIdx[at][q] = (q < 10) ? sn[(m0 + at) * KNN + q] : dn[(m0 + at) * KNN + q - 10];
    }
    {
        const float* atoms = p ? atoms1 : atoms0;
        for (int i = tid; i < 384; i += 256)
            ((float4*)sWv)[i] = ((const float4*)Wv)[i];
        if (tid < 96)
            ((float4*)sAt)[tid] = *(const float4*)&atoms[(size_t)m0 * NCAT + tid * 4];
    }
    __syncthreads();

    // ---- phase A: gather -> sZ (8 threads/atom, 16 cols each) ----
    {
        const int at = tid >> 3, c = tid & 7;
        const int a = m0 + at;
        float ss[16], dd[16];
#pragma unroll
        for (int e = 0; e < 16; ++e) { ss[e] = 0.f; dd[e] = 0.f; }
        int sc = 0, dc = 0;
#pragma unroll
        for (int n = 0; n < KNN; ++n) {
            int is = sIdx[at][n];
            if (is > -1) {
                sc++;
                uint4 v0 = *(const uint4*)&SDp[(size_t)is * 256 + c * 16];
                uint4 v1 = *(const uint4*)&SDp[(size_t)is * 256 + c * 16 + 8];
                uint32_t vv[8] = {v0.x, v0.y, v0.z, v0.w, v1.x, v1.y, v1.z, v1.w};
#pragma unroll
                for (int q = 0; q < 8; ++q) { ss[2*q] += bflo(vv[q]); ss[2*q+1] += bfhi(vv[q]); }
            }
        }
#pragma unroll
        for (int n = 0; n < KNN; ++n) {
            int id = sIdx[at][10 + n];
            if (id > -1) {
                dc++;
                uint4 v0 = *(const uint4*)&SDp[(size_t)id * 256 + 128 + c * 16];
                uint4 v1 = *(const uint4*)&SDp[(size_t)id * 256 + 128 + c * 16 + 8];
                uint32_t vv[8] = {v0.x, v0.y, v0.z, v0.w, v1.x, v1.y, v1.z, v1.w};
#pragma unroll
                for (int q = 0; q < 8; ++q) { dd[2*q] += bflo(vv[q]); dd[2*q+1] += bfhi(vv[q]); }
            }
        }
        const float rs = 1.f / (sc > 0 ? (float)sc : 1.f);
        const float rd = 1.f / (dc > 0 ? (float)dc : 1.f);
        float ov[16];
        {
            const size_t base = (size_t)a * FF + c * 16;
            float4 q0 = *(const float4*)&ACCp[base];
            float4 q1 = *(const float4*)&ACCp[base + 4];
            float4 q2 = *(const float4*)&ACCp[base + 8];
            float4 q3 = *(const float4*)&ACCp[base + 12];
            ov[0]=q0.x; ov[1]=q0.y; ov[2]=q0.z; ov[3]=q0.w;
            ov[4]=q1.x; ov[5]=q1.y; ov[6]=q1.z; ov[7]=q1.w;
            ov[8]=q2.x; ov[9]=q2.y; ov[10]=q2.z; ov[11]=q2.w;
            ov[12]=q3.x; ov[13]=q3.y; ov[14]=q3.z; ov[15]=q3.w;
        }
#pragma unroll
        for (int cc = 0; cc < NCAT; ++cc) {
            float ac = sAt[at * NCAT + cc];
            const float* wp = &sWv[cc * FF + c * 16];
#pragma unroll
            for (int e = 0; e < 16; ++e) ov[e] = fmaf(ac, wp[e], ov[e]);
        }
        ushort8v z0, z1;
#pragma unroll
        for (int e = 0; e < 8; ++e) {
            z0[e] = bfc(fmaxf(fmaf(ss[e],     rs, fmaf(dd[e],     rd, ov[e])),     0.f));
            z1[e] = bfc(fmaxf(fmaf(ss[e + 8], rs, fmaf(dd[e + 8], rd, ov[e + 8])), 0.f));
        }
        int bb = at * 256 + c * 32;
        *(ushort8v*)((char*)sZ + ( bb        ^ ((at & 7) << 4))) = z0;
        *(ushort8v*)((char*)sZ + ((bb + 16) ^ ((at & 7) << 4))) = z1;
    }

    // ---- phase B: Z @ {Wsv, Wsr2, Wdr2} ----
    for (int mat = 0; mat < 3; ++mat) {
        __syncthreads();   // sZ ready (mat 0) / previous compute done
#pragma unroll
        for (int t = 0; t < 2; ++t) {
            const char* bs = (const char*)Bt3 + (size_t)(mat * 2 + t) * 16384 + tid * 16;
#pragma unroll
            for (int q = 0; q < 4; ++q) gload16((char*)sB[t] + tid * 16 + q * 4096, bs + q * 4096);
        }
        __syncthreads();   // gloads drained

        floatx4 acc[2][2];
#pragma unroll
        for (int mt = 0; mt < 2; ++mt)
#pragma unroll
            for (int nt = 0; nt < 2; ++nt) acc[mt][nt] = (floatx4){0.f, 0.f, 0.f, 0.f};

#pragma unroll
        for (int t = 0; t < 2; ++t)
#pragma unroll
            for (int ks = 0; ks < 2; ++ks) {
                short8 ah[2], bh[2];
                const int kb = ks * 64 + (l >> 4) * 16;
#pragma unroll
                for (int mt = 0; mt < 2; ++mt) {
                    int row = mt * 16 + (l & 15);
                    ah[mt] = *(const short8*)((char*)sZ +
                             ((row * 256 + t * 128 + kb) ^ ((row & 7) << 4)));
                }
#pragma unroll
                for (int nt = 0; nt < 2; ++nt) {
                    int row = w * 32 + nt * 16 + (l & 15);
                    bh[nt] = *(const short8*)((char*)sB[t] + ((row * 128 + kb) ^ ((row & 7) << 4)));
                }
#pragma unroll
                for (int mt = 0; mt < 2; ++mt)
#pragma unroll
                    for (int nt = 0; nt < 2; ++nt)
                        acc[mt][nt] = __builtin_amdgcn_mfma_f32_16x16x32_bf16(ah[mt], bh[nt], acc[mt][nt], 0, 0, 0);
            }

#pragma unroll
        for (int mt = 0; mt < 2; ++mt)
#pragma unroll
            for (int nt = 0; nt < 2; ++nt)
#pragma unroll
                for (int r = 0; r < 4; ++r) {
                    int row = m0 + mt * 16 + (l >> 4) * 4 + r;
                    int col = w * 32 + nt * 16 + (l & 15);
                    float v = acc[mt][nt][r];
                    if (mat == 0) ACCp[(size_t)row * FF + col] = v;
                    else          SD2p[(size_t)row * 256 + (mat - 1) * FF + col] = bfc(v);
                }
    }
}

// ---------------------------------------------------------------------------
// Gather 2 fused with residue mean: one block per residue (40 atoms).
// Reads ACC (layer-2 Wsv out) + SD2 (layer-2 S/D).
// ---------------------------------------------------------------------------
__global__ void __launch_bounds__(256)
k_gather_res(const float* __restrict__ ACC, const unsigned short* __restrict__ SD2,
             const int* __restrict__ sn0, const int* __restrict__ dn0,
             const int* __restrict__ sn1, const int* __restrict__ dn1,
             float* __restrict__ R12)
{
    __shared__ int sIdx[APR][20];      // 3.2 KB
    __shared__ float zpart[16][128];   // 8 KB
    const int tid = threadIdx.x;
    const int p = blockIdx.y, r = blockIdx.x;
    const int* sn = p ? sn1 : sn0;
    const int* dn = p ? dn1 : dn0;
    const float* ACCp = ACC + (size_t)p * 2048000;
    const unsigned short* SDp = SD2 + (size_t)p * 4096000;
    const int aBase = r * APR;

    for (int t = tid; t < APR * 20; t += 256) {
        int at = t / 20, q = t - at * 20;
        sIdx[at][q] = (q < 10) ? sn[(aBase + at) * KNN + q] : dn[(aBase + at) * KNN + q - 10];
    }
    __syncthreads();

    const int at = tid >> 4, c8 = tid & 15;
    float zs[8] = {0,0,0,0,0,0,0,0};
#pragma unroll
    for (int rep = 0; rep < 3; ++rep) {
        int ai = at + rep * 16;
        if (ai < APR) {
            int a = aBase + ai;
            float ss[8] = {0,0,0,0,0,0,0,0}, dd[8] = {0,0,0,0,0,0,0,0};
            int sc = 0, dc = 0;
#pragma unroll
            for (int n = 0; n < KNN; ++n) {
                int is = sIdx[ai][n];
                if (is > -1) {
                    sc++;
                    uint4 v = *(const uint4*)&SDp[(size_t)is * 256 + c8 * 8];
                    uint32_t vv[4] = {v.x, v.y, v.z, v.w};
#pragma unroll
                    for (int q = 0; q < 4; ++q) { ss[2*q] += bflo(vv[q]); ss[2*q+1] += bfhi(vv[q]); }
                }
            }
#pragma unroll
            for (int n = 0; n < KNN; ++n) {
                int id = sIdx[ai][10 + n];
                if (id > -1) {
                    dc++;
                    uint4 v = *(const uint4*)&SDp[(size_t)id * 256 + 128 + c8 * 8];
                    uint32_t vv[4] = {v.x, v.y, v.z, v.w};
#pragma unroll
                    for (int q = 0; q < 4; ++q) { dd[2*q] += bflo(vv[q]); dd[2*q+1] += bfhi(vv[q]); }
                }
            }
            const float rs = 1.f / (sc > 0 ? (float)sc : 1.f);
            const float rd = 1.f / (dc > 0 ? (float)dc : 1.f);
            float4 a0v = *(const float4*)&ACCp[(size_t)a * FF + c8 * 8];
            float4 a1v = *(const float4*)&ACCp[(size_t)a * FF + c8 * 8 + 4];
            float ov[8] = {a0v.x, a0v.y, a0v.z, a0v.w, a1v.x, a1v.y, a1v.z, a1v.w};
#pragma unroll
            for (int e = 0; e < 8; ++e)
                zs[e] += fmaxf(fmaf(ss[e], rs, fmaf(dd[e], rd, ov[e])), 0.f);
        }
    }
    *(float4*)&zpart[at][c8 * 8]     = (float4){zs[0], zs[1], zs[2], zs[3]};
    *(float4*)&zpart[at][c8 * 8 + 4] = (float4){zs[4], zs[5], zs[6], zs[7]};
    __syncthreads();
#pragma unroll
    for (int s = 8; s > 0; s >>= 1) {
        if (at < s) {
            float4 x0 = *(const float4*)&zpart[at + s][c8 * 8];
            float4 x1 = *(const float4*)&zpart[at + s][c8 * 8 + 4];
            float4 y0 = *(const float4*)&zpart[at][c8 * 8];
            float4 y1 = *(const float4*)&zpart[at][c8 * 8 + 4];
            y0.x += x0.x; y0.y += x0.y; y0.z += x0.z; y0.w += x0.w;
            y1.x += x1.x; y1.y += x1.y; y1.z += x1.z; y1.w += x1.w;
            *(float4*)&zpart[at][c8 * 8]     = y0;
            *(float4*)&zpart[at][c8 * 8 + 4] = y1;
        }
        __syncthreads();
    }
    if (at == 0) {
        float* R = R12 + (size_t)p * 51200 + (size_t)r * FF;
        const float inv = 1.0f / APR;
#pragma unroll
        for (int e = 0; e < 8; ++e) R[c8 * 8 + e] = zpart[0][c8 * 8 + e] * inv;
    }
}

// ---------------------------------------------------------------------------
// A1[i] = r1[i] @ Wf1[:128,:] + bf1 ;  B1[j] = r2[j] @ Wf1[128:,:]
// ---------------------------------------------------------------------------
__global__ void k_pairprep(const float* __restrict__ R1, const float* __restrict__ R2,
                           const float* __restrict__ Wf1, const float* __restrict__ bf1,
                           float* __restrict__ A1, float* __restrict__ B1)
{
    __shared__ float r1s[FF], r2s[FF];
    int i = blockIdx.x, o = threadIdx.x;   // 256 threads
    if (o < FF) r1s[o] = R1[i * FF + o];
    else        r2s[o - FF] = R2[i * FF + (o - FF)];
    __syncthreads();
    float sa = bf1[o], sb = 0.f;
#pragma unroll 8
    for (int k = 0; k < FF; ++k) {
        sa = fmaf(r1s[k], Wf1[(size_t)k * DF1 + o], sa);
        sb = fmaf(r2s[k], Wf1[(size_t)(FF + k) * DF1 + o], sb);
    }
    A1[(size_t)i * DF1 + o] = sa;
    B1[(size_t)i * DF1 + o] = sb;
}

// ---------------------------------------------------------------------------
// Pair MLP via MFMA, register-built H.
// ---------------------------------------------------------------------------
__global__ void __launch_bounds__(256)
k_pairs_mfma(const float* __restrict__ A1, const float* __restrict__ B1,
             const unsigned short* __restrict__ W2T,
             const float* __restrict__ bf2, const float* __restrict__ Wf3,
             const float* __restrict__ bf3, float* __restrict__ out)
{
    __shared__ __align__(16) float sA1[16 * 256];            // 16 KB linear
    __shared__ __align__(16) float sB1[16 * 256];            // 16 KB, XOR (row&7)<<5
    __shared__ __align__(16) unsigned short sW[64 * 256];    // 32 KB, XOR (n&7)<<4
    const int tid = threadIdx.x, l = tid & 63, w = tid >> 6;
    const int i0 = blockIdx.x * 16, j0 = blockIdx.y * 16;

    for (int idx = tid; idx < 64 * 32; idx += 256) {
        int row = idx >> 5, c = idx & 31;
        int ba = (row * 512 + c * 16) ^ ((row & 7) << 4);
        *(uint4*)((char*)sW + ba) = *(const uint4*)(W2T + row * 256 + c * 8);
    }
    {
        int row = tid >> 4;
#pragma unroll
        for (int pass = 0; pass < 4; ++pass) {
            int coff = pass * 64 + (tid & 15) * 4;
            *(float4*)((char*)sA1 + row * 1024 + coff * 4) =
                *(const float4*)&A1[(size_t)(i0 + row) * DF1 + coff];
            int bb = (row * 1024 + coff * 4) ^ ((row & 7) << 5);
            *(float4*)((char*)sB1 + bb) =
                *(const float4*)&B1[(size_t)(j0 + row) * DF1 + coff];
        }
    }
    __syncthreads();

    floatx4 acc[4][4];
#pragma unroll
    for (int mt = 0; mt < 4; ++mt)
#pragma unroll
        for (int nt = 0; nt < 4; ++nt) acc[mt][nt] = (floatx4){0.f, 0.f, 0.f, 0.f};

    float b2r[4], w3r[4];
#pragma unroll
    for (int nt = 0; nt < 4; ++nt) {
        b2r[nt] = bf2[nt * 16 + (l & 15)];
        w3r[nt] = Wf3[nt * 16 + (l & 15)];
    }

    const int rB = l & 15, kq = l >> 4;
#pragma unroll
    for (int kc = 0; kc < 4; ++kc)
#pragma unroll
        for (int ks = 0; ks < 2; ++ks) {
            const int kfb = (kc * 64 + ks * 32 + kq * 8) * 4;
            float4 b1a = *(const float4*)((char*)sB1 + ((rB * 1024 + kfb)      ^ ((rB & 7) << 5)));
            float4 b1b = *(const float4*)((char*)sB1 + ((rB * 1024 + kfb + 16) ^ ((rB & 7) << 5)));
            short8 afr[4];
#pragma unroll
            for (int mt = 0; mt < 4; ++mt) {
                int rA = w * 4 + mt;
                float4 a1a = *(const float4*)((char*)sA1 + rA * 1024 + kfb);
                float4 a1b = *(const float4*)((char*)sA1 + rA * 1024 + kfb + 16);
                short8 hv;
                hv[0] = (short)bfc(fmaxf(a1a.x + b1a.x, 0.f));
                hv[1] = (short)bfc(fmaxf(a1a.y + b1a.y, 0.f));
                hv[2] = (short)bfc(fmaxf(a1a.z + b1a.z, 0.f));
                hv[3] = (short)bfc(fmaxf(a1a.w + b1a.w, 0.f));
                hv[4] = (short)bfc(fmaxf(a1b.x + b1b.x, 0.f));
                hv[5] = (short)bfc(fmaxf(a1b.y + b1b.y, 0.f));
                hv[6] = (short)bfc(fmaxf(a1b.z + b1b.z, 0.f));
                hv[7] = (short)bfc(fmaxf(a1b.w + b1b.w, 0.f));
                afr[mt] = hv;
            }
            const int kwb = kc * 128 + ks * 64 + kq * 16;
            short8 bfr[4];
#pragma unroll
            for (int nt = 0; nt < 4; ++nt) {
                int n = nt * 16 + (l & 15);
                bfr[nt] = *(const short8*)((char*)sW + ((n * 512 + kwb) ^ ((n & 7) << 4)));
            }
#pragma unroll
            for (int mt = 0; mt < 4; ++mt)
#pragma unroll
                for (int nt = 0; nt < 4; ++nt)
                    acc[mt][nt] = __builtin_amdgcn_mfma_f32_16x16x32_bf16(afr[mt], bfr[nt], acc[mt][nt], 0, 0, 0);
        }

    const float b3 = bf3[0];
#pragma unroll
    for (int mt = 0; mt < 4; ++mt)
#pragma unroll
        for (int r = 0; r < 4; ++r) {
            float s = 0.f;
#pragma unroll
            for (int nt = 0; nt < 4; ++nt)
                s += fmaxf(acc[mt][nt][r] + b2r[nt], 0.f) * w3r[nt];
            s += __shfl_xor(s, 1); s += __shfl_xor(s, 2);
            s += __shfl_xor(s, 4); s += __shfl_xor(s, 8);
            if ((l & 15) == 0) {
                int p = w * 64 + mt * 16 + (l >> 4) * 4 + r;
                out[(size_t)(i0 + (p >> 4)) * NRES + j0 + (p & 15)] = s + b3;
            }
        }
}

// ---------------------------------------------------------------------------
extern "C" void kernel_launch(void* const* d_in, const int* in_sizes, int n_in,
                              void* d_out, int out_size, void* d_ws, size_t ws_size,
                              hipStream_t stream)
{
    const float* atoms0    = (const float*)d_in[0];
    const float* residues0 = (const float*)d_in[1];
    const int*   same0     = (const int*)d_in[2];
    const int*   diff0     = (const int*)d_in[3];
    const float* atoms1    = (const float*)d_in[5];
    const float* residues1 = (const float*)d_in[6];
    const int*   same1     = (const int*)d_in[7];
    const int*   diff1     = (const int*)d_in[8];
    const float* Wv   = (const float*)d_in[10];
    const float* Wr   = (const float*)d_in[11];
    const float* Wsr1 = (const float*)d_in[12];
    const float* Wdr1 = (const float*)d_in[13];
    const float* Wsv  = (const float*)d_in[14];
    const float* Wsr2 = (const float*)d_in[15];
    const float* Wdr2 = (const float*)d_in[16];
    const float* Wf1  = (const float*)d_in[17];
    const float* bf1  = (const float*)d_in[18];
    const float* Wf2  = (const float*)d_in[19];
    const float* bf2  = (const float*)d_in[20];
    const float* Wf3  = (const float*)d_in[21];
    const float* bf3  = (const float*)d_in[22];

    float* ws  = (float*)d_ws;
    float* ACC = ws;                                         // 2 x 2,048,000 f
    unsigned short* SD  = (unsigned short*)(ws + 4096000);   // 2 x 4,096,000 u16 (layer-1)
    unsigned short* SD2 = (unsigned short*)(ws + 8192000);   // 2 x 4,096,000 u16 (layer-2)
    float* R12 = ws + 12288000;                              // 2 x 51,200 f
    float* A1  = ws + 12390400;                              // 102,400 f
    float* B1  = ws + 12492800;                              // 102,400 f
    unsigned short* WrT = (unsigned short*)(ws + 12595200);  // 131,072 u16
    unsigned short* Bt3 = (unsigned short*)(ws + 12660736);  //  49,152 u16
    unsigned short* W2T = (unsigned short*)(ws + 12685312);  //  16,384 u16

    k_prep<<<152, 256, 0, stream>>>(Wr, Wsv, Wsr2, Wdr2, Wf2, WrT, Bt3, W2T);
    k_mega1<<<dim3(500, 2), 256, 0, stream>>>(residues0, residues1, WrT,
                                              atoms0, atoms1, Wsr1, Wdr1, ACC, SD);
    k_gl2<<<dim3(500, 2), 256, 0, stream>>>(ACC, SD, Bt3, same0, diff0, same1, diff1,
                                            atoms0, atoms1, Wv, SD2);
    k_gather_res<<<dim3(NRES, 2), 256, 0, stream>>>(ACC, SD2, same0, diff0, same1, diff1, R12);
    k_pairprep<<<NRES, 256, 0, stream>>>(R12, R12 + 51200, Wf1, bf1, A1, B1);
    k_pairs_mfma<<<dim3(25, 25), 256, 0, stream>>>(A1, B1, W2T, bf2, Wf3, bf3, (float*)d_out);
}